// Round 1
// baseline (2244.795 us; speedup 1.0000x reference)
//
#include <hip/hip_runtime.h>
#include <hip/hip_bf16.h>
#include <math.h>

#define DM   1024
#define DF   4096
#define NH   8
#define NB   4
#define NS   2048
#define MT   (NB*NS)   // 8192 tokens

typedef __bf16 bf16;
typedef __bf16 bf16x8 __attribute__((ext_vector_type(8)));
typedef float  f32x4  __attribute__((ext_vector_type(4)));

typedef __attribute__((address_space(3))) unsigned int u32_lds;
typedef const __attribute__((address_space(1))) void cv_glob;

__device__ __forceinline__ void gload16(const void* g, const void* l) {
    // LDS generic pointer: low 32 bits are the LDS byte offset (aperture is 4GB-aligned).
    __builtin_amdgcn_global_load_lds(
        (cv_glob*)(unsigned long long)g,
        (u32_lds*)(unsigned int)(unsigned long long)l,
        16, 0, 0);
}

__device__ __forceinline__ float gelu_f(float x) {
    return 0.5f * x * (1.0f + erff(x * 0.70710678118654752f));
}

// ---------------- x f32 -> bf16, 8 elems/thread ----------------
__global__ __launch_bounds__(256) void k_cvtx(const float* __restrict__ in, bf16* __restrict__ out) {
    long i = ((long)blockIdx.x * 256 + threadIdx.x) * 8;
    float4 a = *(const float4*)(in + i);
    float4 b = *(const float4*)(in + i + 4);
    bf16x8 o;
    o[0]=(bf16)a.x; o[1]=(bf16)a.y; o[2]=(bf16)a.z; o[3]=(bf16)a.w;
    o[4]=(bf16)b.x; o[5]=(bf16)b.y; o[6]=(bf16)b.z; o[7]=(bf16)b.w;
    *(bf16x8*)(out + i) = o;
}

// ------------- tiled transpose+convert: out[c*outStride + r] = (bf16)in[r*C + c] -------------
__global__ __launch_bounds__(256) void k_tcvt(const float* __restrict__ in, bf16* __restrict__ out,
                                              int R, int C, long outStride, long inBatch, long outBatch) {
    __shared__ float t[32][33];
    const float* ip = in + (long)blockIdx.z * inBatch;
    bf16* op = out + (long)blockIdx.z * outBatch;
    int c0 = blockIdx.x * 32, r0 = blockIdx.y * 32;
    int x = threadIdx.x, y = threadIdx.y;   // block (32,8)
    #pragma unroll
    for (int i = 0; i < 4; ++i) t[y + 8*i][x] = ip[(long)(r0 + y + 8*i) * C + c0 + x];
    __syncthreads();
    #pragma unroll
    for (int i = 0; i < 4; ++i) op[(long)(c0 + y + 8*i) * outStride + r0 + x] = (bf16)t[x][y + 8*i];
}

// ---------------- state projection: sp[b][d] = rs[b]@Ws[:,d] + bs[d] ----------------
__global__ __launch_bounds__(256) void k_sproj(const float* __restrict__ rs, const float* __restrict__ Ws,
                                               const float* __restrict__ bs, float* __restrict__ sp) {
    // grid (16, 4): 16 d-groups of 64, batch; 4 k-slices of 256 per block
    int d  = blockIdx.x * 64 + (threadIdx.x & 63);
    int ks = (threadIdx.x >> 6) * 256;
    const float* r = rs + blockIdx.y * DM;
    float acc = 0.f;
    for (int k = ks; k < ks + 256; ++k) acc += r[k] * Ws[(long)k * DM + d];
    __shared__ float red[256];
    red[threadIdx.x] = acc;
    __syncthreads();
    if (threadIdx.x < 64) {
        float v = red[threadIdx.x] + red[threadIdx.x + 64] + red[threadIdx.x + 128] + red[threadIdx.x + 192] + bs[d];
        sp[blockIdx.y * DM + d] = v;
    }
}

// ---------------- gate: logits = g@Wg + bg; softmax -> wout [t][8] ----------------
__global__ __launch_bounds__(256) void k_gate(const bf16* __restrict__ g, const float* __restrict__ Wg,
                                              const float* __restrict__ bg, float* __restrict__ wout) {
    int lane = threadIdx.x & 63, wid = threadIdx.x >> 6;
    long t = (long)blockIdx.x * 4 + wid;            // one token per wave
    const bf16* gr = g + t * DM + lane * 16;
    bf16x8 v0 = *(const bf16x8*)gr;
    bf16x8 v1 = *(const bf16x8*)(gr + 8);
    float s0=0,s1=0,s2=0,s3=0,s4=0,s5=0,s6=0,s7=0;
    #pragma unroll
    for (int i = 0; i < 16; ++i) {
        float gv = (float)((i < 8) ? v0[i] : v1[i - 8]);
        const float4* wr = (const float4*)(Wg + (long)(lane * 16 + i) * NH);
        float4 wa = wr[0], wb = wr[1];
        s0 += gv*wa.x; s1 += gv*wa.y; s2 += gv*wa.z; s3 += gv*wa.w;
        s4 += gv*wb.x; s5 += gv*wb.y; s6 += gv*wb.z; s7 += gv*wb.w;
    }
    #pragma unroll
    for (int off = 32; off >= 1; off >>= 1) {
        s0 += __shfl_xor(s0, off); s1 += __shfl_xor(s1, off);
        s2 += __shfl_xor(s2, off); s3 += __shfl_xor(s3, off);
        s4 += __shfl_xor(s4, off); s5 += __shfl_xor(s5, off);
        s6 += __shfl_xor(s6, off); s7 += __shfl_xor(s7, off);
    }
    float l0=s0+bg[0], l1=s1+bg[1], l2=s2+bg[2], l3=s3+bg[3];
    float l4=s4+bg[4], l5=s5+bg[5], l6=s6+bg[6], l7=s7+bg[7];
    float m = fmaxf(fmaxf(fmaxf(l0,l1),fmaxf(l2,l3)), fmaxf(fmaxf(l4,l5),fmaxf(l6,l7)));
    float e0=expf(l0-m), e1=expf(l1-m), e2=expf(l2-m), e3=expf(l3-m);
    float e4=expf(l4-m), e5=expf(l5-m), e6=expf(l6-m), e7=expf(l7-m);
    float inv = 1.f / (e0+e1+e2+e3+e4+e5+e6+e7);
    if (lane == 0) {
        float* wo = wout + t * NH;
        wo[0]=e0*inv; wo[1]=e1*inv; wo[2]=e2*inv; wo[3]=e3*inv;
        wo[4]=e4*inv; wo[5]=e5*inv; wo[6]=e6*inv; wo[7]=e7*inv;
    }
}

// ---------------- m97-structure 128x128x64 bf16 MFMA GEMM, templated epilogue ----------------
// EPI 0: C = gelu(acc + bias[col] + sp[b][col])           -> bf16 outH       (input proj)
// EPI 1: C = wts[t][h] * gelu(acc + b1[h][col])           -> bf16 outH       (hidden)
// EPI 2: C = acc (+ sum_h wts[t][h]*b2[h][col] if INIT) (+= outF if ACC) -> f32 outF  (output)
template<int EPI>
__global__ __launch_bounds__(256) void k_gemm(
    const bf16* __restrict__ A, long lda,
    const bf16* __restrict__ Bt, long ldb, long bHead,
    int K, int head0,
    bf16* __restrict__ outH, float* __restrict__ outF, long ldc, long cHead,
    const float* __restrict__ bias, long biasHead,
    const float* __restrict__ aux1, const float* __restrict__ aux2, int flags)
{
    __shared__ __align__(16) unsigned char lsA[128 * 128];   // [128 rows][64 k] bf16 = 16 KB
    __shared__ __align__(16) unsigned char lsB[128 * 128];   // [128 n-rows][64 k] bf16 = 16 KB
    const int tid = threadIdx.x, lane = tid & 63, wid = tid >> 6;
    const int h = head0 + blockIdx.z;
    const long tileM = (long)blockIdx.x * 128;
    const long tileN = (long)blockIdx.y * 128;
    const bf16* Ab = A + tileM * lda;
    const bf16* Bb = Bt + (long)h * bHead + tileN * ldb;

    f32x4 acc[4][4];
    #pragma unroll
    for (int m = 0; m < 4; ++m)
        #pragma unroll
        for (int n = 0; n < 4; ++n) { f32x4 z = {0.f, 0.f, 0.f, 0.f}; acc[m][n] = z; }

    const int wr = wid >> 1, wc = wid & 1;   // 2x2 waves, each 64x64
    const int ktn = K >> 6;
    for (int kt = 0; kt < ktn; ++kt) {
        const long kO = (long)kt * 64;
        #pragma unroll
        for (int is = 0; is < 4; ++is) {
            const int o   = is * 4096 + tid * 16;     // byte offset in 16KB tile
            const int row = o >> 7;
            const int ce  = (o & 127) >> 1;           // element within 64-k row
            gload16(Ab + (long)row * lda + kO + ce, lsA + is * 4096 + wid * 1024);
            gload16(Bb + (long)row * ldb + kO + ce, lsB + is * 4096 + wid * 1024);
        }
        __syncthreads();
        #pragma unroll
        for (int kk = 0; kk < 2; ++kk) {
            const int kb = kk * 64 + (lane >> 4) * 16;
            bf16x8 av[4], bv[4];
            #pragma unroll
            for (int m = 0; m < 4; ++m)
                av[m] = *(const bf16x8*)(lsA + ((wr * 64 + m * 16 + (lane & 15)) << 7) + kb);
            #pragma unroll
            for (int n = 0; n < 4; ++n)
                bv[n] = *(const bf16x8*)(lsB + ((wc * 64 + n * 16 + (lane & 15)) << 7) + kb);
            #pragma unroll
            for (int m = 0; m < 4; ++m)
                #pragma unroll
                for (int n = 0; n < 4; ++n)
                    acc[m][n] = __builtin_amdgcn_mfma_f32_16x16x32_bf16(av[m], bv[n], acc[m][n], 0, 0, 0);
        }
        __syncthreads();
    }

    // epilogue: C/D layout col = lane&15, row = (lane>>4)*4 + j
    const long rowBase = tileM + wr * 64;
    const int  colBase = (int)tileN + wc * 64;
    #pragma unroll
    for (int m = 0; m < 4; ++m) {
        const long r0 = rowBase + m * 16 + ((lane >> 4) * 4);
        #pragma unroll
        for (int n = 0; n < 4; ++n) {
            const int col = colBase + n * 16 + (lane & 15);
            #pragma unroll
            for (int j = 0; j < 4; ++j) {
                const long t = r0 + j;
                float v = acc[m][n][j];
                if constexpr (EPI == 0) {
                    const int b = (int)(t >> 11);           // SEQ = 2048
                    v += bias[col] + aux1[(long)b * DM + col];
                    v = gelu_f(v);
                    outH[t * ldc + col] = (bf16)v;
                } else if constexpr (EPI == 1) {
                    v += bias[(long)h * biasHead + col];
                    v = gelu_f(v);
                    v *= aux1[t * NH + h];
                    outH[t * ldc + (long)h * cHead + col] = (bf16)v;
                } else {
                    if (flags & 1) {
                        float bsum = 0.f;
                        #pragma unroll
                        for (int hh = 0; hh < NH; ++hh)
                            bsum += aux1[t * NH + hh] * aux2[(long)hh * DM + col];
                        v += bsum;
                    }
                    if (flags & 2) v += outF[t * ldc + col];
                    outF[t * ldc + col] = v;
                }
            }
        }
    }
}

extern "C" void kernel_launch(void* const* d_in, const int* in_sizes, int n_in,
                              void* d_out, int out_size, void* d_ws, size_t ws_size,
                              hipStream_t stream)
{
    const float* x  = (const float*)d_in[0];
    const float* rs = (const float*)d_in[1];
    const float* W1 = (const float*)d_in[2];
    const float* b1 = (const float*)d_in[3];
    const float* W2 = (const float*)d_in[4];
    const float* b2 = (const float*)d_in[5];
    const float* Ws = (const float*)d_in[6];
    const float* bs = (const float*)d_in[7];
    const float* Wi = (const float*)d_in[8];
    const float* bi = (const float*)d_in[9];
    const float* Wg = (const float*)d_in[10];
    const float* bg = (const float*)d_in[11];

    float* out  = (float*)d_out;                    // [8192][1024] f32
    float* wout = out + (size_t)MT * DM;            // [8192][8]   f32 (output 1)

    unsigned char* ws = (unsigned char*)d_ws;
    size_t ofs = 0;
    auto alloc = [&](size_t bytes) { void* p = ws + ofs; ofs += (bytes + 255) & ~(size_t)255; return p; };

    bf16*  xbf = (bf16*)alloc((size_t)MT * DM * 2);     // 16.8 MB
    bf16*  WiT = (bf16*)alloc((size_t)DM * DM * 2);     //  2.1 MB
    bf16*  g   = (bf16*)alloc((size_t)MT * DM * 2);     // 16.8 MB
    float* sp  = (float*)alloc((size_t)NB * DM * 4);    // 16 KB

    const size_t SZ_W1T  = (size_t)NH * DF * DM * 2;    // 67.1 MB
    const size_t SZ_W2T  = (size_t)NH * DF * DM * 2;    // 67.1 MB
    const size_t SZ_HPF  = (size_t)MT * NH * DF * 2;    // 536.9 MB
    const bool full = ws_size >= ofs + SZ_W1T + SZ_W2T + SZ_HPF;

    dim3 tb32(32, 8);

    // stage 0: conversions / transposes (independent of projections)
    k_cvtx<<<(MT * DM) / (256 * 8), 256, 0, stream>>>(x, xbf);
    k_tcvt<<<dim3(32, 32, 1), tb32, 0, stream>>>(Wi, WiT, DM, DM, DM, 0, 0);
    k_sproj<<<dim3(16, NB), 256, 0, stream>>>(rs, Ws, bs, sp);

    // stage 1: input proj -> gelu(combined) [bf16 g], then gate weights
    k_gemm<0><<<dim3(MT / 128, DM / 128, 1), 256, 0, stream>>>(
        xbf, DM, WiT, DM, 0, DM, 0, g, nullptr, DM, 0, bi, 0, sp, nullptr, 0);
    k_gate<<<MT / 4, 256, 0, stream>>>(g, Wg, bg, wout);

    if (full) {
        bf16* W1T = (bf16*)alloc(SZ_W1T);   // [h][f][d]
        bf16* W2T = (bf16*)alloc(SZ_W2T);   // [d][h][f]
        bf16* hp  = (bf16*)alloc(SZ_HPF);   // [t][h][f] = w * gelu(x@W1+b1)
        k_tcvt<<<dim3(DF / 32, DM / 32, NH), tb32, 0, stream>>>(
            W1, W1T, DM, DF, DM, (long)DM * DF, (long)DF * DM);
        k_tcvt<<<dim3(DM / 32, DF / 32, NH), tb32, 0, stream>>>(
            W2, W2T, DF, DM, (long)NH * DF, (long)DF * DM, DF);
        k_gemm<1><<<dim3(MT / 128, DF / 128, NH), 256, 0, stream>>>(
            xbf, DM, W1T, DM, (long)DF * DM, DM, 0,
            hp, nullptr, (long)NH * DF, DF, b1, DF, wout, nullptr, 0);
        k_gemm<2><<<dim3(MT / 128, DM / 128, 1), 256, 0, stream>>>(
            hp, (long)NH * DF, W2T, (long)NH * DF, 0, NH * DF, 0,
            nullptr, out, DM, 0, nullptr, 0, wout, b2, 1);
    } else {
        // lean path: one head at a time (~120 MB ws)
        bf16* W1Th = (bf16*)alloc((size_t)DF * DM * 2);   // [f][d]
        bf16* W2Th = (bf16*)alloc((size_t)DF * DM * 2);   // [d][f]
        bf16* hp   = (bf16*)alloc((size_t)MT * DF * 2);   // [t][f]
        for (int h = 0; h < NH; ++h) {
            k_tcvt<<<dim3(DF / 32, DM / 32, 1), tb32, 0, stream>>>(
                W1 + (size_t)h * DM * DF, W1Th, DM, DF, DM, 0, 0);
            k_tcvt<<<dim3(DM / 32, DF / 32, 1), tb32, 0, stream>>>(
                W2 + (size_t)h * DF * DM, W2Th, DF, DM, DF, 0, 0);
            k_gemm<1><<<dim3(MT / 128, DF / 128, 1), 256, 0, stream>>>(
                xbf, DM, W1Th, DM, 0, DM, h,
                hp, nullptr, DF, 0, b1, DF, wout, nullptr, 0);
            k_gemm<2><<<dim3(MT / 128, DM / 128, 1), 256, 0, stream>>>(
                hp, DF, W2Th, DF, 0, DF, 0,
                nullptr, out, DM, 0, nullptr, 0, wout, b2, (h == 0) ? 1 : 2);
        }
    }
    (void)in_sizes; (void)n_in; (void)out_size;
}

// Round 2
// 2208.124 us; speedup vs baseline: 1.0166x; 1.0166x over previous
//
#include <hip/hip_runtime.h>
#include <hip/hip_bf16.h>
#include <math.h>

#define DM   1024
#define DF   4096
#define NH   8
#define NB   4
#define NS   2048
#define MT   (NB*NS)   // 8192 tokens

typedef __bf16 bf16;
typedef __bf16 bf16x8 __attribute__((ext_vector_type(8)));
typedef float  f32x4  __attribute__((ext_vector_type(4)));

typedef __attribute__((address_space(3))) unsigned int u32_lds;
typedef const __attribute__((address_space(1))) void cv_glob;

__device__ __forceinline__ void gload16(const void* g, const void* l) {
    __builtin_amdgcn_global_load_lds(
        (cv_glob*)(unsigned long long)g,
        (u32_lds*)(unsigned int)(unsigned long long)l,
        16, 0, 0);
}

__device__ __forceinline__ float gelu_f(float x) {
    return 0.5f * x * (1.0f + erff(x * 0.70710678118654752f));
}

// SWIZZLE CONVENTION (T2, rule #21 both-sides): every bf16 buffer consumed by
// k_gemm's global_load_lds staging is stored with 16B chunks permuted within
// each 128B (64-element) row-block:  chunk c -> c ^ (row & 7).
// gload_lds copies linearly, so LDS holds the same permutation; ds_read XORs
// byte ^ ((row&7)<<4) to recover logical data. Element-index form of the store
// side: elem e of row r stored at e ^ ((r&7)<<3).

// ---------------- x f32 -> bf16 (swizzled), 8 elems/thread ----------------
__global__ __launch_bounds__(256) void k_cvtx(const float* __restrict__ in, bf16* __restrict__ out) {
    long i = ((long)blockIdx.x * 256 + threadIdx.x) * 8;
    float4 a = *(const float4*)(in + i);
    float4 b = *(const float4*)(in + i + 4);
    bf16x8 o;
    o[0]=(bf16)a.x; o[1]=(bf16)a.y; o[2]=(bf16)a.z; o[3]=(bf16)a.w;
    o[4]=(bf16)b.x; o[5]=(bf16)b.y; o[6]=(bf16)b.z; o[7]=(bf16)b.w;
    long t7 = (i >> 10) & 7;                 // row = token (1024 elems/row)
    *(bf16x8*)(out + (i ^ (t7 << 3))) = o;   // stays 16B-aligned (XOR bits 3..5)
}

// ------------- tiled transpose+convert+swizzle: out[c][r ^ ((c&7)<<3)] = (bf16)in[r*C + c] -------------
__global__ __launch_bounds__(256) void k_tcvt(const float* __restrict__ in, bf16* __restrict__ out,
                                              int R, int C, long outStride, long inBatch, long outBatch) {
    __shared__ float t[32][33];
    const float* ip = in + (long)blockIdx.z * inBatch;
    bf16* op = out + (long)blockIdx.z * outBatch;
    int c0 = blockIdx.x * 32, r0 = blockIdx.y * 32;
    int x = threadIdx.x, y = threadIdx.y;   // block (32,8)
    #pragma unroll
    for (int i = 0; i < 4; ++i) t[y + 8*i][x] = ip[(long)(r0 + y + 8*i) * C + c0 + x];
    __syncthreads();
    // out row index c = c0 + y + 8*i  ->  (c&7) == y  (c0 mult of 32, 8*i keeps bits>=3)
    #pragma unroll
    for (int i = 0; i < 4; ++i) {
        int c = c0 + y + 8*i;
        int rs = (r0 + x) ^ (y << 3);       // swizzled col within row (R mult of 64)
        op[(long)c * outStride + rs] = (bf16)t[x][y + 8*i];
    }
}

// ---------------- state projection: sp[b][d] = rs[b]@Ws[:,d] + bs[d] ----------------
__global__ __launch_bounds__(256) void k_sproj(const float* __restrict__ rs, const float* __restrict__ Ws,
                                               const float* __restrict__ bs, float* __restrict__ sp) {
    int d  = blockIdx.x * 64 + (threadIdx.x & 63);
    int ks = (threadIdx.x >> 6) * 256;
    const float* r = rs + blockIdx.y * DM;
    float acc = 0.f;
    for (int k = ks; k < ks + 256; ++k) acc += r[k] * Ws[(long)k * DM + d];
    __shared__ float red[256];
    red[threadIdx.x] = acc;
    __syncthreads();
    if (threadIdx.x < 64) {
        float v = red[threadIdx.x] + red[threadIdx.x + 64] + red[threadIdx.x + 128] + red[threadIdx.x + 192] + bs[d];
        sp[blockIdx.y * DM + d] = v;
    }
}

// ---------------- gate: logits = g@Wg + bg; softmax -> wout [t][8] (g is UNswizzled) ----------------
__global__ __launch_bounds__(256) void k_gate(const bf16* __restrict__ g, const float* __restrict__ Wg,
                                              const float* __restrict__ bg, float* __restrict__ wout) {
    int lane = threadIdx.x & 63, wid = threadIdx.x >> 6;
    long t = (long)blockIdx.x * 4 + wid;            // one token per wave
    const bf16* gr = g + t * DM + lane * 16;
    bf16x8 v0 = *(const bf16x8*)gr;
    bf16x8 v1 = *(const bf16x8*)(gr + 8);
    float s0=0,s1=0,s2=0,s3=0,s4=0,s5=0,s6=0,s7=0;
    #pragma unroll
    for (int i = 0; i < 16; ++i) {
        float gv = (float)((i < 8) ? v0[i] : v1[i - 8]);
        const float4* wr = (const float4*)(Wg + (long)(lane * 16 + i) * NH);
        float4 wa = wr[0], wb = wr[1];
        s0 += gv*wa.x; s1 += gv*wa.y; s2 += gv*wa.z; s3 += gv*wa.w;
        s4 += gv*wb.x; s5 += gv*wb.y; s6 += gv*wb.z; s7 += gv*wb.w;
    }
    #pragma unroll
    for (int off = 32; off >= 1; off >>= 1) {
        s0 += __shfl_xor(s0, off); s1 += __shfl_xor(s1, off);
        s2 += __shfl_xor(s2, off); s3 += __shfl_xor(s3, off);
        s4 += __shfl_xor(s4, off); s5 += __shfl_xor(s5, off);
        s6 += __shfl_xor(s6, off); s7 += __shfl_xor(s7, off);
    }
    float l0=s0+bg[0], l1=s1+bg[1], l2=s2+bg[2], l3=s3+bg[3];
    float l4=s4+bg[4], l5=s5+bg[5], l6=s6+bg[6], l7=s7+bg[7];
    float m = fmaxf(fmaxf(fmaxf(l0,l1),fmaxf(l2,l3)), fmaxf(fmaxf(l4,l5),fmaxf(l6,l7)));
    float e0=expf(l0-m), e1=expf(l1-m), e2=expf(l2-m), e3=expf(l3-m);
    float e4=expf(l4-m), e5=expf(l5-m), e6=expf(l6-m), e7=expf(l7-m);
    float inv = 1.f / (e0+e1+e2+e3+e4+e5+e6+e7);
    if (lane == 0) {
        float* wo = wout + t * NH;
        wo[0]=e0*inv; wo[1]=e1*inv; wo[2]=e2*inv; wo[3]=e3*inv;
        wo[4]=e4*inv; wo[5]=e5*inv; wo[6]=e6*inv; wo[7]=e7*inv;
    }
}

// ---------------- m97-structure 128x128x64 bf16 MFMA GEMM, swizzled LDS, templated epilogue ----------------
// All A / Bt global buffers are pre-swizzled (see convention above).
// EPI 0: C = gelu(acc + bias[col] + sp[b][col])                  -> bf16 outH (UNswizzled; fed to k_gate)
// EPI 1: C = wts[t][h] * gelu(acc + b1[h][col])                  -> bf16 outH (SWIZZLED; fed back as A)
// EPI 2: C = acc (+ sum_h w*b2 if flags&1) (+= outF if flags&2)  -> f32 outF  (UNswizzled)
template<int EPI>
__global__ __launch_bounds__(256) void k_gemm(
    const bf16* __restrict__ A, long lda,
    const bf16* __restrict__ Bt, long ldb, long bHead,
    int K, int head0,
    bf16* __restrict__ outH, float* __restrict__ outF, long ldc, long cHead,
    const float* __restrict__ bias, long biasHead,
    const float* __restrict__ aux1, const float* __restrict__ aux2, int flags)
{
    __shared__ __align__(16) unsigned char lsA[128 * 128];   // [128 rows][64 k] bf16 = 16 KB
    __shared__ __align__(16) unsigned char lsB[128 * 128];
    const int tid = threadIdx.x, lane = tid & 63, wid = tid >> 6;
    const int h = head0 + blockIdx.z;
    const long tileM = (long)blockIdx.x * 128;
    const long tileN = (long)blockIdx.y * 128;
    const bf16* Ab = A + tileM * lda;
    const bf16* Bb = Bt + (long)h * bHead + tileN * ldb;

    f32x4 acc[4][4];
    #pragma unroll
    for (int m = 0; m < 4; ++m)
        #pragma unroll
        for (int n = 0; n < 4; ++n) { f32x4 z = {0.f, 0.f, 0.f, 0.f}; acc[m][n] = z; }

    const int wr = wid >> 1, wc = wid & 1;   // 2x2 waves, each 64x64
    const int swz = (lane & 7) << 4;         // row&7 == lane&7 for all fragment rows
    const int ktn = K >> 6;
    for (int kt = 0; kt < ktn; ++kt) {
        const long kO = (long)kt * 64;
        #pragma unroll
        for (int is = 0; is < 4; ++is) {
            const int o   = is * 4096 + tid * 16;     // byte offset in 16KB tile
            const int row = o >> 7;
            const int ce  = (o & 127) >> 1;           // element within 64-k row (pre-swizzled data)
            gload16(Ab + (long)row * lda + kO + ce, lsA + is * 4096 + wid * 1024);
            gload16(Bb + (long)row * ldb + kO + ce, lsB + is * 4096 + wid * 1024);
        }
        __syncthreads();
        #pragma unroll
        for (int kk = 0; kk < 2; ++kk) {
            const int kb = (kk * 64 + (lane >> 4) * 16) ^ swz;   // de-swizzling read offset
            bf16x8 av[4], bv[4];
            #pragma unroll
            for (int m = 0; m < 4; ++m)
                av[m] = *(const bf16x8*)(lsA + ((wr * 64 + m * 16 + (lane & 15)) << 7) + kb);
            #pragma unroll
            for (int n = 0; n < 4; ++n)
                bv[n] = *(const bf16x8*)(lsB + ((wc * 64 + n * 16 + (lane & 15)) << 7) + kb);
            #pragma unroll
            for (int m = 0; m < 4; ++m)
                #pragma unroll
                for (int n = 0; n < 4; ++n)
                    acc[m][n] = __builtin_amdgcn_mfma_f32_16x16x32_bf16(av[m], bv[n], acc[m][n], 0, 0, 0);
        }
        __syncthreads();
    }

    // epilogue: C/D layout col = lane&15, row = (lane>>4)*4 + j
    const long rowBase = tileM + wr * 64;
    const int  colBase = (int)tileN + wc * 64;
    #pragma unroll
    for (int m = 0; m < 4; ++m) {
        const long r0 = rowBase + m * 16 + ((lane >> 4) * 4);
        #pragma unroll
        for (int n = 0; n < 4; ++n) {
            const int col = colBase + n * 16 + (lane & 15);
            #pragma unroll
            for (int j = 0; j < 4; ++j) {
                const long t = r0 + j;
                float v = acc[m][n][j];
                if constexpr (EPI == 0) {
                    const int b = (int)(t >> 11);           // SEQ = 2048
                    v += bias[col] + aux1[(long)b * DM + col];
                    v = gelu_f(v);
                    outH[t * ldc + col] = (bf16)v;          // unswizzled
                } else if constexpr (EPI == 1) {
                    v += bias[(long)h * biasHead + col];
                    v = gelu_f(v);
                    v *= aux1[t * NH + h];
                    const int col2 = col ^ (((int)t & 7) << 3);   // swizzled store
                    outH[t * ldc + (long)blockIdx.z * cHead + col2] = (bf16)v;
                } else {
                    if (flags & 1) {
                        float bsum = 0.f;
                        #pragma unroll
                        for (int hh = 0; hh < NH; ++hh)
                            bsum += aux1[t * NH + hh] * aux2[(long)hh * DM + col];
                        v += bsum;
                    }
                    if (flags & 2) v += outF[t * ldc + col];
                    outF[t * ldc + col] = v;
                }
            }
        }
    }
}

extern "C" void kernel_launch(void* const* d_in, const int* in_sizes, int n_in,
                              void* d_out, int out_size, void* d_ws, size_t ws_size,
                              hipStream_t stream)
{
    const float* x  = (const float*)d_in[0];
    const float* rs = (const float*)d_in[1];
    const float* W1 = (const float*)d_in[2];
    const float* b1 = (const float*)d_in[3];
    const float* W2 = (const float*)d_in[4];
    const float* b2 = (const float*)d_in[5];
    const float* Ws = (const float*)d_in[6];
    const float* bs = (const float*)d_in[7];
    const float* Wi = (const float*)d_in[8];
    const float* bi = (const float*)d_in[9];
    const float* Wg = (const float*)d_in[10];
    const float* bg = (const float*)d_in[11];

    float* out  = (float*)d_out;                    // [8192][1024] f32
    float* wout = out + (size_t)MT * DM;            // [8192][8]   f32 (output 1)

    unsigned char* ws = (unsigned char*)d_ws;
    size_t ofs = 0;
    auto alloc = [&](size_t bytes) { void* p = ws + ofs; ofs += (bytes + 255) & ~(size_t)255; return p; };

    bf16*  xbf = (bf16*)alloc((size_t)MT * DM * 2);     // 16.8 MB (swizzled)
    bf16*  WiT = (bf16*)alloc((size_t)DM * DM * 2);     //  2.1 MB (swizzled)
    bf16*  g   = (bf16*)alloc((size_t)MT * DM * 2);     // 16.8 MB (linear)
    float* sp  = (float*)alloc((size_t)NB * DM * 4);    // 16 KB

    const size_t SZ_WT  = (size_t)NH * DF * DM * 2;     // 67.1 MB (each full transposed weight)
    const size_t SZ_HP1 = (size_t)MT * DF * 2;          // 67.1 MB (hp per head-slot)

    // largest head-group whose hp fits alongside both full transposed weights
    int HG = 0;
    for (int hg = NH; hg >= 1; hg >>= 1)
        if (ofs + 2 * SZ_WT + (size_t)hg * SZ_HP1 <= ws_size) { HG = hg; break; }

    dim3 tb32(32, 8);

    // stage 0: conversions / transposes / projections
    k_cvtx<<<(MT * DM) / (256 * 8), 256, 0, stream>>>(x, xbf);
    k_tcvt<<<dim3(32, 32, 1), tb32, 0, stream>>>(Wi, WiT, DM, DM, DM, 0, 0);
    k_sproj<<<dim3(16, NB), 256, 0, stream>>>(rs, Ws, bs, sp);

    // stage 1: input proj -> gelu(combined) [bf16 g], then gate weights
    k_gemm<0><<<dim3(MT / 128, DM / 128, 1), 256, 0, stream>>>(
        xbf, DM, WiT, DM, 0, DM, 0, g, nullptr, DM, 0, bi, 0, sp, nullptr, 0);
    k_gate<<<MT / 4, 256, 0, stream>>>(g, Wg, bg, wout);

    if (HG >= 1) {
        bf16* W1T = (bf16*)alloc(SZ_WT);                 // [h][f][d]   (swizzled rows f)
        bf16* W2T = (bf16*)alloc(SZ_WT);                 // [d][h*f]    (swizzled rows d)
        bf16* hp  = (bf16*)alloc((size_t)HG * SZ_HP1);   // [t][HG*f]   (swizzled rows t)
        k_tcvt<<<dim3(DF / 32, DM / 32, NH), tb32, 0, stream>>>(
            W1, W1T, DM, DF, DM, (long)DM * DF, (long)DF * DM);
        k_tcvt<<<dim3(DM / 32, DF / 32, NH), tb32, 0, stream>>>(
            W2, W2T, DF, DM, (long)NH * DF, (long)DF * DM, DF);
        const int nGroups = NH / HG;
        for (int gr = 0; gr < nGroups; ++gr) {
            k_gemm<1><<<dim3(MT / 128, DF / 128, HG), 256, 0, stream>>>(
                xbf, DM, W1T, DM, (long)DF * DM, DM, gr * HG,
                hp, nullptr, (long)HG * DF, DF, b1, DF, wout, nullptr, 0);
            k_gemm<2><<<dim3(MT / 128, DM / 128, 1), 256, 0, stream>>>(
                hp, (long)HG * DF, W2T + (size_t)gr * HG * DF, (long)NH * DF, 0, HG * DF, 0,
                nullptr, out, DM, 0, nullptr, 0, wout, b2, (gr == 0) ? 1 : 2);
        }
    } else {
        // ultra-lean: one head at a time with per-head transposes (~120 MB ws)
        bf16* W1Th = (bf16*)alloc((size_t)DF * DM * 2);   // [f][d]
        bf16* W2Th = (bf16*)alloc((size_t)DF * DM * 2);   // [d][f]
        bf16* hp   = (bf16*)alloc(SZ_HP1);                // [t][f]
        for (int h = 0; h < NH; ++h) {
            k_tcvt<<<dim3(DF / 32, DM / 32, 1), tb32, 0, stream>>>(
                W1 + (size_t)h * DM * DF, W1Th, DM, DF, DM, 0, 0);
            k_tcvt<<<dim3(DM / 32, DF / 32, 1), tb32, 0, stream>>>(
                W2 + (size_t)h * DF * DM, W2Th, DF, DM, DF, 0, 0);
            k_gemm<1><<<dim3(MT / 128, DF / 128, 1), 256, 0, stream>>>(
                xbf, DM, W1Th, DM, 0, DM, h,
                hp, nullptr, DF, 0, b1, DF, wout, nullptr, 0);
            k_gemm<2><<<dim3(MT / 128, DM / 128, 1), 256, 0, stream>>>(
                hp, DF, W2Th, DF, 0, DF, 0,
                nullptr, out, DM, 0, nullptr, 0, wout, b2, (h == 0) ? 1 : 2);
        }
    }
    (void)in_sizes; (void)n_in; (void)out_size;
}

// Round 3
// 1957.450 us; speedup vs baseline: 1.1468x; 1.1281x over previous
//
#include <hip/hip_runtime.h>
#include <hip/hip_bf16.h>
#include <math.h>

#define DM   1024
#define DF   4096
#define NH   8
#define NB   4
#define NS   2048
#define MT   (NB*NS)   // 8192 tokens

typedef __bf16 bf16;
typedef __bf16 bf16x4 __attribute__((ext_vector_type(4)));
typedef __bf16 bf16x8 __attribute__((ext_vector_type(8)));
typedef float  f32x4  __attribute__((ext_vector_type(4)));

typedef __attribute__((address_space(3))) unsigned int u32_lds;
typedef const __attribute__((address_space(1))) void cv_glob;

__device__ __forceinline__ void gload16(const void* g, const void* l) {
    __builtin_amdgcn_global_load_lds(
        (cv_glob*)(unsigned long long)g,
        (u32_lds*)(unsigned int)(unsigned long long)l,
        16, 0, 0);
}

__device__ __forceinline__ float gelu_f(float x) {
    return 0.5f * x * (1.0f + erff(x * 0.70710678118654752f));
}

// SWIZZLE CONVENTION (T2, rule #21 both-sides): every bf16 buffer consumed by
// the GEMM's global_load_lds staging is stored with 16B chunks permuted within
// each 128B (64-element) row-block:  chunk c -> c ^ (row & 7)   (elem form:
// elem e of row r stored at e ^ ((r&7)<<3)). gload_lds copies linearly, so
// LDS holds the same permutation; ds_read XORs byte ^ ((row&7)<<4).
// Proven in R2: SQ_LDS_BANK_CONFLICT == 0.

// ---------------- x f32 -> bf16 (swizzled), 8 elems/thread ----------------
__global__ __launch_bounds__(256) void k_cvtx(const float* __restrict__ in, bf16* __restrict__ out) {
    long i = ((long)blockIdx.x * 256 + threadIdx.x) * 8;
    float4 a = *(const float4*)(in + i);
    float4 b = *(const float4*)(in + i + 4);
    bf16x8 o;
    o[0]=(bf16)a.x; o[1]=(bf16)a.y; o[2]=(bf16)a.z; o[3]=(bf16)a.w;
    o[4]=(bf16)b.x; o[5]=(bf16)b.y; o[6]=(bf16)b.z; o[7]=(bf16)b.w;
    long t7 = (i >> 10) & 7;                 // row = token (1024 elems/row)
    *(bf16x8*)(out + (i ^ (t7 << 3))) = o;
}

// ---- transpose+convert+swizzle, 64x64 tile: out[c][(r)^((c&7)<<3)] = (bf16)in[r*C+c] ----
__global__ __launch_bounds__(256) void k_tcvt2(const float* __restrict__ in, bf16* __restrict__ out,
                                               int C, long outStride, long inBatch, long outBatch) {
    __shared__ float t[64][65];
    const float* ip = in + (long)blockIdx.z * inBatch;
    bf16* op = out + (long)blockIdx.z * outBatch;
    const int c0 = blockIdx.x * 64, r0 = blockIdx.y * 64;
    const int tid = threadIdx.x;
    const int rr = tid >> 4, cc = tid & 15;
    #pragma unroll
    for (int it = 0; it < 4; ++it) {
        const int r = rr + 16 * it;
        float4 v = *(const float4*)(ip + (long)(r0 + r) * C + c0 + cc * 4);
        t[r][cc*4+0] = v.x; t[r][cc*4+1] = v.y; t[r][cc*4+2] = v.z; t[r][cc*4+3] = v.w;
    }
    __syncthreads();
    #pragma unroll
    for (int it = 0; it < 4; ++it) {
        const int oc = rr + 16 * it;           // out row within tile (= source col)
        const int e  = cc * 4;                 // elem within out row (= source row - r0)
        bf16 tmp[4];
        #pragma unroll
        for (int j = 0; j < 4; ++j) tmp[j] = (bf16)t[e + j][oc];
        const int rs = e ^ ((oc & 7) << 3);    // swizzled (r0 mult of 64)
        *(bf16x4*)(op + (long)(c0 + oc) * outStride + r0 + rs) = *(bf16x4*)tmp;
    }
}

// ---------------- state projection: sp[b][d] = rs[b]@Ws[:,d] + bs[d] ----------------
__global__ __launch_bounds__(256) void k_sproj(const float* __restrict__ rs, const float* __restrict__ Ws,
                                               const float* __restrict__ bs, float* __restrict__ sp) {
    int d  = blockIdx.x * 64 + (threadIdx.x & 63);
    int ks = (threadIdx.x >> 6) * 256;
    const float* r = rs + blockIdx.y * DM;
    float acc = 0.f;
    for (int k = ks; k < ks + 256; ++k) acc += r[k] * Ws[(long)k * DM + d];
    __shared__ float red[256];
    red[threadIdx.x] = acc;
    __syncthreads();
    if (threadIdx.x < 64) {
        float v = red[threadIdx.x] + red[threadIdx.x + 64] + red[threadIdx.x + 128] + red[threadIdx.x + 192] + bs[d];
        sp[blockIdx.y * DM + d] = v;
    }
}

// ---------------- gate: logits = g@Wg + bg; softmax -> wout [t][8] (g is UNswizzled) ----------------
__global__ __launch_bounds__(256) void k_gate(const bf16* __restrict__ g, const float* __restrict__ Wg,
                                              const float* __restrict__ bg, float* __restrict__ wout) {
    int lane = threadIdx.x & 63, wid = threadIdx.x >> 6;
    long t = (long)blockIdx.x * 4 + wid;            // one token per wave
    const bf16* gr = g + t * DM + lane * 16;
    bf16x8 v0 = *(const bf16x8*)gr;
    bf16x8 v1 = *(const bf16x8*)(gr + 8);
    float s0=0,s1=0,s2=0,s3=0,s4=0,s5=0,s6=0,s7=0;
    #pragma unroll
    for (int i = 0; i < 16; ++i) {
        float gv = (float)((i < 8) ? v0[i] : v1[i - 8]);
        const float4* wr = (const float4*)(Wg + (long)(lane * 16 + i) * NH);
        float4 wa = wr[0], wb = wr[1];
        s0 += gv*wa.x; s1 += gv*wa.y; s2 += gv*wa.z; s3 += gv*wa.w;
        s4 += gv*wb.x; s5 += gv*wb.y; s6 += gv*wb.z; s7 += gv*wb.w;
    }
    #pragma unroll
    for (int off = 32; off >= 1; off >>= 1) {
        s0 += __shfl_xor(s0, off); s1 += __shfl_xor(s1, off);
        s2 += __shfl_xor(s2, off); s3 += __shfl_xor(s3, off);
        s4 += __shfl_xor(s4, off); s5 += __shfl_xor(s5, off);
        s6 += __shfl_xor(s6, off); s7 += __shfl_xor(s7, off);
    }
    float l0=s0+bg[0], l1=s1+bg[1], l2=s2+bg[2], l3=s3+bg[3];
    float l4=s4+bg[4], l5=s5+bg[5], l6=s6+bg[6], l7=s7+bg[7];
    float m = fmaxf(fmaxf(fmaxf(l0,l1),fmaxf(l2,l3)), fmaxf(fmaxf(l4,l5),fmaxf(l6,l7)));
    float e0=expf(l0-m), e1=expf(l1-m), e2=expf(l2-m), e3=expf(l3-m);
    float e4=expf(l4-m), e5=expf(l5-m), e6=expf(l6-m), e7=expf(l7-m);
    float inv = 1.f / (e0+e1+e2+e3+e4+e5+e6+e7);
    if (lane == 0) {
        float* wo = wout + t * NH;
        wo[0]=e0*inv; wo[1]=e1*inv; wo[2]=e2*inv; wo[3]=e3*inv;
        wo[4]=e4*inv; wo[5]=e5*inv; wo[6]=e6*inv; wo[7]=e7*inv;
    }
}

// ============ pipelined 256x128x64 bf16 MFMA GEMM (T3+T4 counted vmcnt, T5, T2 swizzle) ============
// 8 waves (2M x 4N), wave output 128x32. LDS: 3-deep K-tile buffers (A 3x32K, B 3x16K = 144KB).
// Per tile: 6 global_load_lds (A 4 + B 2), 20 ds_read_b128, 32 MFMA.
// Pipeline: while computing tile t, stage t+2; vmcnt(12) before the barrier retires tile t's 6
// loads in EVERY wave -> after s_barrier, tile t is collectively resident. No vmcnt(0) drain.
// EPI 0: C = gelu(acc + bias[col] + sp[b][col])                  -> bf16 outH (UNswizzled)
// EPI 1: C = wts[t][h] * gelu(acc + b1[h][col])                  -> bf16 outH (SWIZZLED)
// EPI 2: C = acc (+ sum_h w*b2 if flags&1) (+= outF if flags&2)  -> f32 outF  (UNswizzled)
template<int EPI>
__global__ __launch_bounds__(512, 2) void k_gemmP(
    const bf16* __restrict__ A, long lda,
    const bf16* __restrict__ Bt, long ldb, long bHead,
    int K, int head0, int gm, int gn,
    bf16* __restrict__ outH, float* __restrict__ outF, long ldc, long cHead,
    const float* __restrict__ bias, long biasHead,
    const float* __restrict__ aux1, const float* __restrict__ aux2, int flags)
{
    __shared__ __align__(16) unsigned char lsA[3][32 * 1024];
    __shared__ __align__(16) unsigned char lsB[3][16 * 1024];
    const int tid = threadIdx.x, lane = tid & 63, wid = tid >> 6;

    // bijective XCD-chunked block swizzle (grid size is a multiple of 8)
    const int cpx = (int)gridDim.x >> 3;
    const int id  = blockIdx.x;
    const int wg  = (id & 7) * cpx + (id >> 3);
    const int bx  = wg % gm;                 // M tile (fastest -> shares B panel within XCD)
    const int by  = (wg / gm) % gn;          // N tile
    const int bz  = wg / (gm * gn);          // head
    const int h   = head0 + bz;
    const long tileM = (long)bx * 256;
    const long tileN = (long)by * 128;
    const bf16* Ab = A + tileM * lda;
    const bf16* Bb = Bt + (long)h * bHead + tileN * ldb;

    const int wr = wid >> 2, wc = wid & 3;   // 2 x 4 waves
    const int swz = (lane & 7) << 4;

    f32x4 acc[8][2];
    #pragma unroll
    for (int m = 0; m < 8; ++m)
        #pragma unroll
        for (int n = 0; n < 2; ++n) { f32x4 z = {0.f,0.f,0.f,0.f}; acc[m][n] = z; }

    auto STAGE = [&](int t) {
        const int buf = t % 3;
        const long kO = (long)t * 64;
        #pragma unroll
        for (int is = 0; is < 4; ++is) {
            const int o   = is * 8192 + tid * 16;
            const int row = o >> 7;
            const int ce  = (o & 127) >> 1;
            gload16(Ab + (long)row * lda + kO + ce, lsA[buf] + o);
        }
        #pragma unroll
        for (int is = 0; is < 2; ++is) {
            const int o   = is * 8192 + tid * 16;
            const int row = o >> 7;
            const int ce  = (o & 127) >> 1;
            gload16(Bb + (long)row * ldb + kO + ce, lsB[buf] + o);
        }
    };

    auto COMPUTE = [&](int t) {
        const unsigned char* As = lsA[t % 3];
        const unsigned char* Bs = lsB[t % 3];
        bf16x8 av[2][8], bv[2][2];
        #pragma unroll
        for (int kk = 0; kk < 2; ++kk) {
            const int kb = (kk * 64 + (lane >> 4) * 16) ^ swz;
            #pragma unroll
            for (int m = 0; m < 8; ++m)
                av[kk][m] = *(const bf16x8*)(As + ((wr * 128 + m * 16 + (lane & 15)) << 7) + kb);
            #pragma unroll
            for (int n = 0; n < 2; ++n)
                bv[kk][n] = *(const bf16x8*)(Bs + ((wc * 32 + n * 16 + (lane & 15)) << 7) + kb);
        }
        __builtin_amdgcn_s_setprio(1);
        #pragma unroll
        for (int kk = 0; kk < 2; ++kk)
            #pragma unroll
            for (int m = 0; m < 8; ++m)
                #pragma unroll
                for (int n = 0; n < 2; ++n)
                    acc[m][n] = __builtin_amdgcn_mfma_f32_16x16x32_bf16(av[kk][m], bv[kk][n], acc[m][n], 0, 0, 0);
        __builtin_amdgcn_s_setprio(0);
    };

    const int NT = K >> 6;                   // >= 3 for all call sites (min K = 1024)
    STAGE(0); STAGE(1);
    for (int t = 0; t < NT - 2; ++t) {
        STAGE(t + 2);
        asm volatile("s_waitcnt vmcnt(12)" ::: "memory");
        __builtin_amdgcn_s_barrier();
        __builtin_amdgcn_sched_barrier(0);
        COMPUTE(t);
        __builtin_amdgcn_sched_barrier(0);
        __builtin_amdgcn_s_barrier();
    }
    asm volatile("s_waitcnt vmcnt(6)" ::: "memory");
    __builtin_amdgcn_s_barrier();
    __builtin_amdgcn_sched_barrier(0);
    COMPUTE(NT - 2);
    __builtin_amdgcn_sched_barrier(0);
    __builtin_amdgcn_s_barrier();
    asm volatile("s_waitcnt vmcnt(0)" ::: "memory");
    __builtin_amdgcn_s_barrier();
    __builtin_amdgcn_sched_barrier(0);
    COMPUTE(NT - 1);

    // epilogue: C/D layout col = lane&15, row = (lane>>4)*4 + j
    const long rowBase = tileM + wr * 128;
    const int  colBase = (int)tileN + wc * 32;
    #pragma unroll
    for (int m = 0; m < 8; ++m) {
        const long r0 = rowBase + m * 16 + ((lane >> 4) * 4);
        #pragma unroll
        for (int n = 0; n < 2; ++n) {
            const int col = colBase + n * 16 + (lane & 15);
            #pragma unroll
            for (int j = 0; j < 4; ++j) {
                const long tk = r0 + j;
                float v = acc[m][n][j];
                if constexpr (EPI == 0) {
                    const int b = (int)(tk >> 11);          // SEQ = 2048
                    v += bias[col] + aux1[(long)b * DM + col];
                    v = gelu_f(v);
                    outH[tk * ldc + col] = (bf16)v;
                } else if constexpr (EPI == 1) {
                    v += bias[(long)h * biasHead + col];
                    v = gelu_f(v);
                    v *= aux1[tk * NH + h];
                    const int col2 = col ^ (((int)tk & 7) << 3);   // swizzled store
                    outH[tk * ldc + (long)bz * cHead + col2] = (bf16)v;
                } else {
                    if (flags & 1) {
                        float bsum = 0.f;
                        #pragma unroll
                        for (int hh = 0; hh < NH; ++hh)
                            bsum += aux1[tk * NH + hh] * aux2[(long)hh * DM + col];
                        v += bsum;
                    }
                    if (flags & 2) v += outF[tk * ldc + col];
                    outF[tk * ldc + col] = v;
                }
            }
        }
    }
}

extern "C" void kernel_launch(void* const* d_in, const int* in_sizes, int n_in,
                              void* d_out, int out_size, void* d_ws, size_t ws_size,
                              hipStream_t stream)
{
    const float* x  = (const float*)d_in[0];
    const float* rs = (const float*)d_in[1];
    const float* W1 = (const float*)d_in[2];
    const float* b1 = (const float*)d_in[3];
    const float* W2 = (const float*)d_in[4];
    const float* b2 = (const float*)d_in[5];
    const float* Ws = (const float*)d_in[6];
    const float* bs = (const float*)d_in[7];
    const float* Wi = (const float*)d_in[8];
    const float* bi = (const float*)d_in[9];
    const float* Wg = (const float*)d_in[10];
    const float* bg = (const float*)d_in[11];

    float* out  = (float*)d_out;                    // [8192][1024] f32
    float* wout = out + (size_t)MT * DM;            // [8192][8]   f32 (output 1)

    unsigned char* ws = (unsigned char*)d_ws;
    size_t ofs = 0;
    auto alloc = [&](size_t bytes) { void* p = ws + ofs; ofs += (bytes + 255) & ~(size_t)255; return p; };

    bf16*  xbf = (bf16*)alloc((size_t)MT * DM * 2);     // 16.8 MB (swizzled)
    bf16*  WiT = (bf16*)alloc((size_t)DM * DM * 2);     //  2.1 MB (swizzled)
    bf16*  g   = (bf16*)alloc((size_t)MT * DM * 2);     // 16.8 MB (linear)
    float* sp  = (float*)alloc((size_t)NB * DM * 4);    // 16 KB

    const size_t SZ_WT  = (size_t)NH * DF * DM * 2;     // 67.1 MB
    const size_t SZ_HP1 = (size_t)MT * DF * 2;          // 67.1 MB per head-slot

    int HG = 0;
    for (int hg = NH; hg >= 1; hg >>= 1)
        if (ofs + 2 * SZ_WT + (size_t)hg * SZ_HP1 <= ws_size) { HG = hg; break; }

    // stage 0: conversions / transposes / projections
    k_cvtx<<<(MT * DM) / (256 * 8), 256, 0, stream>>>(x, xbf);
    k_tcvt2<<<dim3(DM / 64, DM / 64, 1), 256, 0, stream>>>(Wi, WiT, DM, DM, 0, 0);
    k_sproj<<<dim3(16, NB), 256, 0, stream>>>(rs, Ws, bs, sp);

    // stage 1: input proj -> gelu(combined) [bf16 g], then gate weights
    k_gemmP<0><<<(MT / 256) * (DM / 128), 512, 0, stream>>>(
        xbf, DM, WiT, DM, 0, DM, 0, MT / 256, DM / 128,
        g, nullptr, DM, 0, bi, 0, sp, nullptr, 0);
    k_gate<<<MT / 4, 256, 0, stream>>>(g, Wg, bg, wout);

    if (HG >= 1) {
        bf16* W1T = (bf16*)alloc(SZ_WT);                 // [h][f][d]   (swizzled rows f)
        bf16* W2T = (bf16*)alloc(SZ_WT);                 // [d][h*f]    (swizzled rows d)
        bf16* hp  = (bf16*)alloc((size_t)HG * SZ_HP1);   // [t][HG*f]   (swizzled rows t)
        k_tcvt2<<<dim3(DF / 64, DM / 64, NH), 256, 0, stream>>>(
            W1, W1T, DF, DM, (long)DM * DF, (long)DF * DM);
        k_tcvt2<<<dim3(DM / 64, DF / 64, NH), 256, 0, stream>>>(
            W2, W2T, DM, (long)NH * DF, (long)DF * DM, DF);
        const int nGroups = NH / HG;
        for (int gr = 0; gr < nGroups; ++gr) {
            k_gemmP<1><<<(MT / 256) * (DF / 128) * HG, 512, 0, stream>>>(
                xbf, DM, W1T, DM, (long)DF * DM, DM, gr * HG, MT / 256, DF / 128,
                hp, nullptr, (long)HG * DF, DF, b1, DF, wout, nullptr, 0);
            k_gemmP<2><<<(MT / 256) * (DM / 128), 512, 0, stream>>>(
                hp, (long)HG * DF, W2T + (size_t)gr * HG * DF, (long)NH * DF, 0, HG * DF, 0,
                MT / 256, DM / 128,
                nullptr, out, DM, 0, nullptr, 0, wout, b2, (gr == 0) ? 1 : 2);
        }
    } else {
        // ultra-lean: one head at a time with per-head transposes (~120 MB ws)
        bf16* W1Th = (bf16*)alloc((size_t)DF * DM * 2);   // [f][d]
        bf16* W2Th = (bf16*)alloc((size_t)DF * DM * 2);   // [d][f]
        bf16* hp   = (bf16*)alloc(SZ_HP1);                // [t][f]
        for (int hh = 0; hh < NH; ++hh) {
            k_tcvt2<<<dim3(DF / 64, DM / 64, 1), 256, 0, stream>>>(
                W1 + (size_t)hh * DM * DF, W1Th, DF, DM, 0, 0);
            k_tcvt2<<<dim3(DM / 64, DF / 64, 1), 256, 0, stream>>>(
                W2 + (size_t)hh * DF * DM, W2Th, DM, DF, 0, 0);
            k_gemmP<1><<<(MT / 256) * (DF / 128), 512, 0, stream>>>(
                xbf, DM, W1Th, DM, 0, DM, hh, MT / 256, DF / 128,
                hp, nullptr, DF, 0, b1, DF, wout, nullptr, 0);
            k_gemmP<2><<<(MT / 256) * (DM / 128), 512, 0, stream>>>(
                hp, DF, W2Th, DF, 0, DF, 0, MT / 256, DM / 128,
                nullptr, out, DM, 0, nullptr, 0, wout, b2, (hh == 0) ? 1 : 2);
        }
    }
    (void)in_sizes; (void)n_in; (void)out_size;
}

// Round 4
// 1942.286 us; speedup vs baseline: 1.1557x; 1.0078x over previous
//
#include <hip/hip_runtime.h>
#include <hip/hip_bf16.h>
#include <math.h>

#define DM   1024
#define DF   4096
#define NH   8
#define NB   4
#define NS   2048
#define MT   (NB*NS)   // 8192 tokens

typedef __bf16 bf16;
typedef __bf16 bf16x4 __attribute__((ext_vector_type(4)));
typedef __bf16 bf16x8 __attribute__((ext_vector_type(8)));
typedef float  f32x4  __attribute__((ext_vector_type(4)));

typedef __attribute__((address_space(3))) unsigned int u32_lds;
typedef const __attribute__((address_space(1))) void cv_glob;

__device__ __forceinline__ void gload16(const void* g, const void* l) {
    __builtin_amdgcn_global_load_lds(
        (cv_glob*)(unsigned long long)g,
        (u32_lds*)(unsigned int)(unsigned long long)l,
        16, 0, 0);
}

__device__ __forceinline__ float gelu_f(float x) {
    return 0.5f * x * (1.0f + erff(x * 0.70710678118654752f));
}

// SWIZZLE CONVENTION (T2, rule #21 both-sides): every bf16 buffer consumed by
// the GEMM's global_load_lds staging is stored with 16B chunks permuted within
// each 128B (64-element) row-block:  chunk c -> c ^ (row & 7)   (elem form:
// elem e of row r stored at e ^ ((r&7)<<3)). gload_lds copies linearly, so
// LDS holds the same permutation; ds_read XORs byte ^ ((row&7)<<4).
// Proven in R2/R3: SQ_LDS_BANK_CONFLICT == 0.

// ---------------- x f32 -> bf16 (swizzled), 8 elems/thread ----------------
__global__ __launch_bounds__(256) void k_cvtx(const float* __restrict__ in, bf16* __restrict__ out) {
    long i = ((long)blockIdx.x * 256 + threadIdx.x) * 8;
    float4 a = *(const float4*)(in + i);
    float4 b = *(const float4*)(in + i + 4);
    bf16x8 o;
    o[0]=(bf16)a.x; o[1]=(bf16)a.y; o[2]=(bf16)a.z; o[3]=(bf16)a.w;
    o[4]=(bf16)b.x; o[5]=(bf16)b.y; o[6]=(bf16)b.z; o[7]=(bf16)b.w;
    long t7 = (i >> 10) & 7;                 // row = token (1024 elems/row)
    *(bf16x8*)(out + (i ^ (t7 << 3))) = o;
}

// ---- transpose+convert+swizzle, 64x64 tile: out[c][(r)^((c&7)<<3)] = (bf16)in[r*C+c] ----
__global__ __launch_bounds__(256) void k_tcvt2(const float* __restrict__ in, bf16* __restrict__ out,
                                               int C, long outStride, long inBatch, long outBatch) {
    __shared__ float t[64][65];
    const float* ip = in + (long)blockIdx.z * inBatch;
    bf16* op = out + (long)blockIdx.z * outBatch;
    const int c0 = blockIdx.x * 64, r0 = blockIdx.y * 64;
    const int tid = threadIdx.x;
    const int rr = tid >> 4, cc = tid & 15;
    #pragma unroll
    for (int it = 0; it < 4; ++it) {
        const int r = rr + 16 * it;
        float4 v = *(const float4*)(ip + (long)(r0 + r) * C + c0 + cc * 4);
        t[r][cc*4+0] = v.x; t[r][cc*4+1] = v.y; t[r][cc*4+2] = v.z; t[r][cc*4+3] = v.w;
    }
    __syncthreads();
    #pragma unroll
    for (int it = 0; it < 4; ++it) {
        const int oc = rr + 16 * it;           // out row within tile (= source col)
        const int e  = cc * 4;                 // elem within out row (= source row - r0)
        bf16 tmp[4];
        #pragma unroll
        for (int j = 0; j < 4; ++j) tmp[j] = (bf16)t[e + j][oc];
        const int rs = e ^ ((oc & 7) << 3);    // swizzled (r0 mult of 64)
        *(bf16x4*)(op + (long)(c0 + oc) * outStride + r0 + rs) = *(bf16x4*)tmp;
    }
}

// ---------------- state projection: sp[b][d] = rs[b]@Ws[:,d] + bs[d] ----------------
__global__ __launch_bounds__(256) void k_sproj(const float* __restrict__ rs, const float* __restrict__ Ws,
                                               const float* __restrict__ bs, float* __restrict__ sp) {
    int d  = blockIdx.x * 64 + (threadIdx.x & 63);
    int ks = (threadIdx.x >> 6) * 256;
    const float* r = rs + blockIdx.y * DM;
    float acc = 0.f;
    for (int k = ks; k < ks + 256; ++k) acc += r[k] * Ws[(long)k * DM + d];
    __shared__ float red[256];
    red[threadIdx.x] = acc;
    __syncthreads();
    if (threadIdx.x < 64) {
        float v = red[threadIdx.x] + red[threadIdx.x + 64] + red[threadIdx.x + 128] + red[threadIdx.x + 192] + bs[d];
        sp[blockIdx.y * DM + d] = v;
    }
}

// ---------------- gate: logits = g@Wg + bg; softmax -> wout [t][8] (g is UNswizzled) ----------------
__global__ __launch_bounds__(256) void k_gate(const bf16* __restrict__ g, const float* __restrict__ Wg,
                                              const float* __restrict__ bg, float* __restrict__ wout) {
    int lane = threadIdx.x & 63, wid = threadIdx.x >> 6;
    long t = (long)blockIdx.x * 4 + wid;            // one token per wave
    const bf16* gr = g + t * DM + lane * 16;
    bf16x8 v0 = *(const bf16x8*)gr;
    bf16x8 v1 = *(const bf16x8*)(gr + 8);
    float s0=0,s1=0,s2=0,s3=0,s4=0,s5=0,s6=0,s7=0;
    #pragma unroll
    for (int i = 0; i < 16; ++i) {
        float gv = (float)((i < 8) ? v0[i] : v1[i - 8]);
        const float4* wr = (const float4*)(Wg + (long)(lane * 16 + i) * NH);
        float4 wa = wr[0], wb = wr[1];
        s0 += gv*wa.x; s1 += gv*wa.y; s2 += gv*wa.z; s3 += gv*wa.w;
        s4 += gv*wb.x; s5 += gv*wb.y; s6 += gv*wb.z; s7 += gv*wb.w;
    }
    #pragma unroll
    for (int off = 32; off >= 1; off >>= 1) {
        s0 += __shfl_xor(s0, off); s1 += __shfl_xor(s1, off);
        s2 += __shfl_xor(s2, off); s3 += __shfl_xor(s3, off);
        s4 += __shfl_xor(s4, off); s5 += __shfl_xor(s5, off);
        s6 += __shfl_xor(s6, off); s7 += __shfl_xor(s7, off);
    }
    float l0=s0+bg[0], l1=s1+bg[1], l2=s2+bg[2], l3=s3+bg[3];
    float l4=s4+bg[4], l5=s5+bg[5], l6=s6+bg[6], l7=s7+bg[7];
    float m = fmaxf(fmaxf(fmaxf(l0,l1),fmaxf(l2,l3)), fmaxf(fmaxf(l4,l5),fmaxf(l6,l7)));
    float e0=expf(l0-m), e1=expf(l1-m), e2=expf(l2-m), e3=expf(l3-m);
    float e4=expf(l4-m), e5=expf(l5-m), e6=expf(l6-m), e7=expf(l7-m);
    float inv = 1.f / (e0+e1+e2+e3+e4+e5+e6+e7);
    if (lane == 0) {
        float* wo = wout + t * NH;
        wo[0]=e0*inv; wo[1]=e1*inv; wo[2]=e2*inv; wo[3]=e3*inv;
        wo[4]=e4*inv; wo[5]=e5*inv; wo[6]=e6*inv; wo[7]=e7*inv;
    }
}

// ============ pipelined 256x128x64 bf16 MFMA GEMM (T3+T4 counted vmcnt, T5, T2 swizzle) ============
// 8 waves (2M x 4N), wave output 128x32. LDS: 3-deep K-tile buffers (A 3x32K, B 3x16K = 144KB).
// Per tile: 6 global_load_lds (A 4 + B 2) per thread, vmcnt(12) before the barrier retires tile
// t's loads in EVERY wave -> after s_barrier tile t is collectively resident. No vmcnt(0) drain.
// NFAST=0: bx fastest (M) — use when A is small/L3-resident (panel-sharing across XCDs).
// NFAST=1: by fastest (N) — use when A is huge (hp, 537MB): the gn blocks sharing one A-tile
//          become temporally adjacent so the A-tile is fetched from HBM once and L3-served.
// EPI 0: C = gelu(acc + bias[col] + sp[b][col])                  -> bf16 outH (UNswizzled)
// EPI 1: C = wts[t][h] * gelu(acc + b1[h][col])                  -> bf16 outH (SWIZZLED)
// EPI 2: C = acc (+ sum_h w*b2 if flags&1) (+= outF if flags&2)  -> f32 outF  (UNswizzled)
template<int EPI, int NFAST>
__global__ __launch_bounds__(512, 2) void k_gemmP(
    const bf16* __restrict__ A, long lda,
    const bf16* __restrict__ Bt, long ldb, long bHead,
    int K, int head0, int gm, int gn,
    bf16* __restrict__ outH, float* __restrict__ outF, long ldc, long cHead,
    const float* __restrict__ bias, long biasHead,
    const float* __restrict__ aux1, const float* __restrict__ aux2, int flags)
{
    __shared__ __align__(16) unsigned char lsA[3][32 * 1024];
    __shared__ __align__(16) unsigned char lsB[3][16 * 1024];
    const int tid = threadIdx.x, lane = tid & 63, wid = tid >> 6;

    const int id = blockIdx.x;
    int bx, by, bz;
    if (NFAST) { by = id % gn; bx = (id / gn) % gm; bz = id / (gm * gn); }
    else       { bx = id % gm; by = (id / gm) % gn; bz = id / (gm * gn); }
    const int h   = head0 + bz;
    const long tileM = (long)bx * 256;
    const long tileN = (long)by * 128;
    const bf16* Ab = A + tileM * lda;
    const bf16* Bb = Bt + (long)h * bHead + tileN * ldb;

    const int wr = wid >> 2, wc = wid & 3;   // 2 x 4 waves
    const int swz = (lane & 7) << 4;

    f32x4 acc[8][2];
    #pragma unroll
    for (int m = 0; m < 8; ++m)
        #pragma unroll
        for (int n = 0; n < 2; ++n) { f32x4 z = {0.f,0.f,0.f,0.f}; acc[m][n] = z; }

    auto STAGE = [&](int t) {
        const int buf = t % 3;
        const long kO = (long)t * 64;
        #pragma unroll
        for (int is = 0; is < 4; ++is) {
            const int o   = is * 8192 + tid * 16;
            const int row = o >> 7;
            const int ce  = (o & 127) >> 1;
            gload16(Ab + (long)row * lda + kO + ce, lsA[buf] + o);
        }
        #pragma unroll
        for (int is = 0; is < 2; ++is) {
            const int o   = is * 8192 + tid * 16;
            const int row = o >> 7;
            const int ce  = (o & 127) >> 1;
            gload16(Bb + (long)row * ldb + kO + ce, lsB[buf] + o);
        }
    };

    auto COMPUTE = [&](int t) {
        const unsigned char* As = lsA[t % 3];
        const unsigned char* Bs = lsB[t % 3];
        bf16x8 av[2][8], bv[2][2];
        #pragma unroll
        for (int kk = 0; kk < 2; ++kk) {
            const int kb = (kk * 64 + (lane >> 4) * 16) ^ swz;
            #pragma unroll
            for (int m = 0; m < 8; ++m)
                av[kk][m] = *(const bf16x8*)(As + ((wr * 128 + m * 16 + (lane & 15)) << 7) + kb);
            #pragma unroll
            for (int n = 0; n < 2; ++n)
                bv[kk][n] = *(const bf16x8*)(Bs + ((wc * 32 + n * 16 + (lane & 15)) << 7) + kb);
        }
        __builtin_amdgcn_s_setprio(1);
        #pragma unroll
        for (int kk = 0; kk < 2; ++kk)
            #pragma unroll
            for (int m = 0; m < 8; ++m)
                #pragma unroll
                for (int n = 0; n < 2; ++n)
                    acc[m][n] = __builtin_amdgcn_mfma_f32_16x16x32_bf16(av[kk][m], bv[kk][n], acc[m][n], 0, 0, 0);
        __builtin_amdgcn_s_setprio(0);
    };

    const int NT = K >> 6;                   // >= 3 for all call sites (min K = 1024)
    STAGE(0); STAGE(1);
    for (int t = 0; t < NT - 2; ++t) {
        STAGE(t + 2);
        asm volatile("s_waitcnt vmcnt(12)" ::: "memory");
        __builtin_amdgcn_s_barrier();
        __builtin_amdgcn_sched_barrier(0);
        COMPUTE(t);
        __builtin_amdgcn_sched_barrier(0);
        __builtin_amdgcn_s_barrier();
    }
    asm volatile("s_waitcnt vmcnt(6)" ::: "memory");
    __builtin_amdgcn_s_barrier();
    __builtin_amdgcn_sched_barrier(0);
    COMPUTE(NT - 2);
    __builtin_amdgcn_sched_barrier(0);
    __builtin_amdgcn_s_barrier();
    asm volatile("s_waitcnt vmcnt(0)" ::: "memory");
    __builtin_amdgcn_s_barrier();
    __builtin_amdgcn_sched_barrier(0);
    COMPUTE(NT - 1);

    // epilogue: C/D layout col = lane&15, row = (lane>>4)*4 + j
    const long rowBase = tileM + wr * 128;
    const int  colBase = (int)tileN + wc * 32;
    #pragma unroll
    for (int m = 0; m < 8; ++m) {
        const long r0 = rowBase + m * 16 + ((lane >> 4) * 4);
        #pragma unroll
        for (int n = 0; n < 2; ++n) {
            const int col = colBase + n * 16 + (lane & 15);
            #pragma unroll
            for (int j = 0; j < 4; ++j) {
                const long tk = r0 + j;
                float v = acc[m][n][j];
                if constexpr (EPI == 0) {
                    const int b = (int)(tk >> 11);          // SEQ = 2048
                    v += bias[col] + aux1[(long)b * DM + col];
                    v = gelu_f(v);
                    outH[tk * ldc + col] = (bf16)v;
                } else if constexpr (EPI == 1) {
                    v += bias[(long)h * biasHead + col];
                    v = gelu_f(v);
                    v *= aux1[tk * NH + h];
                    const int col2 = col ^ (((int)tk & 7) << 3);   // swizzled store
                    outH[tk * ldc + (long)bz * cHead + col2] = (bf16)v;
                } else {
                    if (flags & 1) {
                        float bsum = 0.f;
                        #pragma unroll
                        for (int hh = 0; hh < NH; ++hh)
                            bsum += aux1[tk * NH + hh] * aux2[(long)hh * DM + col];
                        v += bsum;
                    }
                    if (flags & 2) v += outF[tk * ldc + col];
                    outF[tk * ldc + col] = v;
                }
            }
        }
    }
}

extern "C" void kernel_launch(void* const* d_in, const int* in_sizes, int n_in,
                              void* d_out, int out_size, void* d_ws, size_t ws_size,
                              hipStream_t stream)
{
    const float* x  = (const float*)d_in[0];
    const float* rs = (const float*)d_in[1];
    const float* W1 = (const float*)d_in[2];
    const float* b1 = (const float*)d_in[3];
    const float* W2 = (const float*)d_in[4];
    const float* b2 = (const float*)d_in[5];
    const float* Ws = (const float*)d_in[6];
    const float* bs = (const float*)d_in[7];
    const float* Wi = (const float*)d_in[8];
    const float* bi = (const float*)d_in[9];
    const float* Wg = (const float*)d_in[10];
    const float* bg = (const float*)d_in[11];

    float* out  = (float*)d_out;                    // [8192][1024] f32
    float* wout = out + (size_t)MT * DM;            // [8192][8]   f32 (output 1)

    unsigned char* ws = (unsigned char*)d_ws;
    size_t ofs = 0;
    auto alloc = [&](size_t bytes) { void* p = ws + ofs; ofs += (bytes + 255) & ~(size_t)255; return p; };

    bf16*  xbf = (bf16*)alloc((size_t)MT * DM * 2);     // 16.8 MB (swizzled)
    bf16*  WiT = (bf16*)alloc((size_t)DM * DM * 2);     //  2.1 MB (swizzled)
    bf16*  g   = (bf16*)alloc((size_t)MT * DM * 2);     // 16.8 MB (linear)
    float* sp  = (float*)alloc((size_t)NB * DM * 4);    // 16 KB

    const size_t SZ_WT  = (size_t)NH * DF * DM * 2;     // 67.1 MB
    const size_t SZ_HP1 = (size_t)MT * DF * 2;          // 67.1 MB per head-slot

    int HG = 0;
    for (int hg = NH; hg >= 1; hg >>= 1)
        if (ofs + 2 * SZ_WT + (size_t)hg * SZ_HP1 <= ws_size) { HG = hg; break; }

    // stage 0: conversions / transposes / projections
    k_cvtx<<<(MT * DM) / (256 * 8), 256, 0, stream>>>(x, xbf);
    k_tcvt2<<<dim3(DM / 64, DM / 64, 1), 256, 0, stream>>>(Wi, WiT, DM, DM, 0, 0);
    k_sproj<<<dim3(16, NB), 256, 0, stream>>>(rs, Ws, bs, sp);

    // stage 1: input proj -> gelu(combined) [bf16 g], then gate weights
    k_gemmP<0, 0><<<(MT / 256) * (DM / 128), 512, 0, stream>>>(
        xbf, DM, WiT, DM, 0, DM, 0, MT / 256, DM / 128,
        g, nullptr, DM, 0, bi, 0, sp, nullptr, 0);
    k_gate<<<MT / 4, 256, 0, stream>>>(g, Wg, bg, wout);

    if (HG >= 1) {
        bf16* W1T = (bf16*)alloc(SZ_WT);                 // [h][f][d]   (swizzled rows f)
        bf16* W2T = (bf16*)alloc(SZ_WT);                 // [d][h*f]    (swizzled rows d)
        bf16* hp  = (bf16*)alloc((size_t)HG * SZ_HP1);   // [t][HG*f]   (swizzled rows t)
        k_tcvt2<<<dim3(DF / 64, DM / 64, NH), 256, 0, stream>>>(
            W1, W1T, DF, DM, (long)DM * DF, (long)DF * DM);
        k_tcvt2<<<dim3(DM / 64, DF / 64, NH), 256, 0, stream>>>(
            W2, W2T, DM, (long)NH * DF, (long)DF * DM, DF);
        const int nGroups = NH / HG;
        for (int gr = 0; gr < nGroups; ++gr) {
            k_gemmP<1, 0><<<(MT / 256) * (DF / 128) * HG, 512, 0, stream>>>(
                xbf, DM, W1T, DM, (long)DF * DM, DM, gr * HG, MT / 256, DF / 128,
                hp, nullptr, (long)HG * DF, DF, b1, DF, wout, nullptr, 0);
            k_gemmP<2, 1><<<(MT / 256) * (DM / 128), 512, 0, stream>>>(
                hp, (long)HG * DF, W2T + (size_t)gr * HG * DF, (long)NH * DF, 0, HG * DF, 0,
                MT / 256, DM / 128,
                nullptr, out, DM, 0, nullptr, 0, wout, b2, (gr == 0) ? 1 : 2);
        }
    } else {
        // ultra-lean: one head at a time with per-head transposes (~120 MB ws)
        bf16* W1Th = (bf16*)alloc((size_t)DF * DM * 2);   // [f][d]
        bf16* W2Th = (bf16*)alloc((size_t)DF * DM * 2);   // [d][f]
        bf16* hp   = (bf16*)alloc(SZ_HP1);                // [t][f]
        for (int hh = 0; hh < NH; ++hh) {
            k_tcvt2<<<dim3(DF / 64, DM / 64, 1), 256, 0, stream>>>(
                W1 + (size_t)hh * DM * DF, W1Th, DF, DM, 0, 0);
            k_tcvt2<<<dim3(DM / 64, DF / 64, 1), 256, 0, stream>>>(
                W2 + (size_t)hh * DF * DM, W2Th, DM, DF, 0, 0);
            k_gemmP<1, 0><<<(MT / 256) * (DF / 128), 512, 0, stream>>>(
                xbf, DM, W1Th, DM, 0, DM, hh, MT / 256, DF / 128,
                hp, nullptr, DF, 0, b1, DF, wout, nullptr, 0);
            k_gemmP<2, 1><<<(MT / 256) * (DM / 128), 512, 0, stream>>>(
                hp, DF, W2Th, DF, 0, DF, 0, MT / 256, DM / 128,
                nullptr, out, DM, 0, nullptr, 0, wout, b2, (hh == 0) ? 1 : 2);
        }
    }
    (void)in_sizes; (void)n_in; (void)out_size;
}

// Round 5
// 1525.734 us; speedup vs baseline: 1.4713x; 1.2730x over previous
//
#include <hip/hip_runtime.h>
#include <hip/hip_bf16.h>
#include <math.h>

#define DM   1024
#define DF   4096
#define NH   8
#define NB   4
#define NS   2048
#define MT   (NB*NS)   // 8192 tokens
#define MQ   2048      // M-split quarter
#define KC   4096      // gemm2 K-split chunk
#define NKS  8         // gemm2 K-splits

typedef __bf16 bf16;
typedef __bf16 bf16x4 __attribute__((ext_vector_type(4)));
typedef __bf16 bf16x8 __attribute__((ext_vector_type(8)));
typedef float  f32x4  __attribute__((ext_vector_type(4)));

typedef __attribute__((address_space(3))) unsigned int u32_lds;
typedef const __attribute__((address_space(1))) void cv_glob;

__device__ __forceinline__ void gload16(const void* g, const void* l) {
    __builtin_amdgcn_global_load_lds(
        (cv_glob*)(unsigned long long)g,
        (u32_lds*)(unsigned int)(unsigned long long)l,
        16, 0, 0);
}

// tanh-form GELU: |gelu_tanh - gelu_erf| <= ~2e-3 absolute; 3x cheaper than erff.
__device__ __forceinline__ float gelu_f(float x) {
    float u = -1.5957691216057308f * fmaf(0.044715f * x, x * x, x);
    return x * __builtin_amdgcn_rcpf(1.f + __expf(u));
}

// SWIZZLE CONVENTION (T2, both-sides): every bf16 buffer consumed by GEMM staging is
// stored with 16B chunks permuted within each 128B (64-elem) row-block:
// elem e of row r stored at e ^ ((r&7)<<3). gload_lds copies linearly; ds_read
// XORs byte ^ ((row&7)<<4). Proven R2-R4: SQ_LDS_BANK_CONFLICT == 0.

// ---------------- x f32 -> bf16 (swizzled rows = tokens) ----------------
__global__ __launch_bounds__(256) void k_cvtx(const float* __restrict__ in, bf16* __restrict__ out) {
    long i = ((long)blockIdx.x * 256 + threadIdx.x) * 8;
    float4 a = *(const float4*)(in + i);
    float4 b = *(const float4*)(in + i + 4);
    bf16x8 o;
    o[0]=(bf16)a.x; o[1]=(bf16)a.y; o[2]=(bf16)a.z; o[3]=(bf16)a.w;
    o[4]=(bf16)b.x; o[5]=(bf16)b.y; o[6]=(bf16)b.z; o[7]=(bf16)b.w;
    long t7 = (i >> 10) & 7;
    *(bf16x8*)(out + (i ^ (t7 << 3))) = o;
}

// ---- transpose+convert+swizzle, 64x64 tile: out[c][r ^ ((c&7)<<3)] = (bf16)in[r*C+c] ----
__global__ __launch_bounds__(256) void k_tcvt2(const float* __restrict__ in, bf16* __restrict__ out,
                                               int C, long outStride, long inBatch, long outBatch) {
    __shared__ float t[64][65];
    const float* ip = in + (long)blockIdx.z * inBatch;
    bf16* op = out + (long)blockIdx.z * outBatch;
    const int c0 = blockIdx.x * 64, r0 = blockIdx.y * 64;
    const int tid = threadIdx.x;
    const int rr = tid >> 4, cc = tid & 15;
    #pragma unroll
    for (int it = 0; it < 4; ++it) {
        const int r = rr + 16 * it;
        float4 v = *(const float4*)(ip + (long)(r0 + r) * C + c0 + cc * 4);
        t[r][cc*4+0] = v.x; t[r][cc*4+1] = v.y; t[r][cc*4+2] = v.z; t[r][cc*4+3] = v.w;
    }
    __syncthreads();
    #pragma unroll
    for (int it = 0; it < 4; ++it) {
        const int oc = rr + 16 * it;
        const int e  = cc * 4;
        bf16 tmp[4];
        #pragma unroll
        for (int j = 0; j < 4; ++j) tmp[j] = (bf16)t[e + j][oc];
        const int rs = e ^ ((oc & 7) << 3);
        *(bf16x4*)(op + (long)(c0 + oc) * outStride + r0 + rs) = *(bf16x4*)tmp;
    }
}

// ---------------- state projection (256 blocks): sp[b][d] = rs[b]@Ws[:,d] + bs[d] ----------------
__global__ __launch_bounds__(256) void k_sproj2(const float* __restrict__ rs, const float* __restrict__ Ws,
                                                const float* __restrict__ bs, float* __restrict__ sp) {
    // grid (DM/16, NB); block: 16 k-slices x 16 d
    const int d0 = blockIdx.x * 16;
    const int ks = threadIdx.x >> 4, dd = threadIdx.x & 15;
    const float* r = rs + blockIdx.y * DM;
    float acc = 0.f;
    #pragma unroll 4
    for (int k = ks * 64; k < ks * 64 + 64; ++k)
        acc += r[k] * Ws[(long)k * DM + d0 + dd];
    __shared__ float red[256];
    red[threadIdx.x] = acc;
    __syncthreads();
    if (threadIdx.x < 16) {
        float v = bs[d0 + threadIdx.x];
        #pragma unroll
        for (int s = 0; s < 16; ++s) v += red[threadIdx.x + 16 * s];
        sp[blockIdx.y * DM + d0 + threadIdx.x] = v;
    }
}

// ---------------- gate: logits = g@Wg + bg; softmax -> wout [t][8] ----------------
__global__ __launch_bounds__(256) void k_gate(const bf16* __restrict__ g, const float* __restrict__ Wg,
                                              const float* __restrict__ bg, float* __restrict__ wout) {
    int lane = threadIdx.x & 63, wid = threadIdx.x >> 6;
    long t = (long)blockIdx.x * 4 + wid;
    const bf16* gr = g + t * DM + lane * 16;
    bf16x8 v0 = *(const bf16x8*)gr;
    bf16x8 v1 = *(const bf16x8*)(gr + 8);
    float s0=0,s1=0,s2=0,s3=0,s4=0,s5=0,s6=0,s7=0;
    #pragma unroll
    for (int i = 0; i < 16; ++i) {
        float gv = (float)((i < 8) ? v0[i] : v1[i - 8]);
        const float4* wr = (const float4*)(Wg + (long)(lane * 16 + i) * NH);
        float4 wa = wr[0], wb = wr[1];
        s0 += gv*wa.x; s1 += gv*wa.y; s2 += gv*wa.z; s3 += gv*wa.w;
        s4 += gv*wb.x; s5 += gv*wb.y; s6 += gv*wb.z; s7 += gv*wb.w;
    }
    #pragma unroll
    for (int off = 32; off >= 1; off >>= 1) {
        s0 += __shfl_xor(s0, off); s1 += __shfl_xor(s1, off);
        s2 += __shfl_xor(s2, off); s3 += __shfl_xor(s3, off);
        s4 += __shfl_xor(s4, off); s5 += __shfl_xor(s5, off);
        s6 += __shfl_xor(s6, off); s7 += __shfl_xor(s7, off);
    }
    float l0=s0+bg[0], l1=s1+bg[1], l2=s2+bg[2], l3=s3+bg[3];
    float l4=s4+bg[4], l5=s5+bg[5], l6=s6+bg[6], l7=s7+bg[7];
    float m = fmaxf(fmaxf(fmaxf(l0,l1),fmaxf(l2,l3)), fmaxf(fmaxf(l4,l5),fmaxf(l6,l7)));
    float e0=expf(l0-m), e1=expf(l1-m), e2=expf(l2-m), e3=expf(l3-m);
    float e4=expf(l4-m), e5=expf(l5-m), e6=expf(l6-m), e7=expf(l7-m);
    float inv = 1.f / (e0+e1+e2+e3+e4+e5+e6+e7);
    if (lane == 0) {
        float* wo = wout + t * NH;
        wo[0]=e0*inv; wo[1]=e1*inv; wo[2]=e2*inv; wo[3]=e3*inv;
        wo[4]=e4*inv; wo[5]=e5*inv; wo[6]=e6*inv; wo[7]=e7*inv;
    }
}

// ============ 256x256x64 bf16 GEMM, 4-phase interleaved (T2+T3+T4+T5) ============
// 8 waves (2M x 4N), wave out 128x64, acc 8x4 f32x4. LDS 2buf x (A 32K + B 32K) = 128 KB.
// One vmcnt(0)+s_barrier per K-tile (loads issued one full tile earlier -> cheap wait).
// 4 phases per tile, no intra-tile barriers: {stage-chunk || ds_read quadrant ||
// sched_barrier || setprio1 16xMFMA setprio0 || sched_barrier}. Reads of phase p+1
// overlap MFMA drain of p; waves drift across phases (2 waves/SIMD).
// EPI 0: gelu(acc+bias[col]+sp[t>>11][col])        -> bf16 outH (unswizzled)
// EPI 1: w[t][col>>12]*gelu(acc+bias[col])         -> bf16 outH (swizzled)
// EPI 2: bz==0: acc+sum_h w*b2 -> outF ; bz>0: acc -> parts[bz-1]
template<int EPI>
__global__ __launch_bounds__(512, 2) void k_g2(
    const bf16* __restrict__ A, long lda,
    const bf16* __restrict__ Bt, long ldb,
    int K, long kcs, int gm, int gn,
    bf16* __restrict__ outH, float* __restrict__ outF, long ldc,
    const float* __restrict__ bias,
    const float* __restrict__ aux1, const float* __restrict__ aux2,
    float* __restrict__ parts, long pStride)
{
    __shared__ __align__(16) unsigned char lsA[2][32 * 1024];
    __shared__ __align__(16) unsigned char lsB[2][32 * 1024];
    const int tid = threadIdx.x, lane = tid & 63, wid = tid >> 6;

    const int id = blockIdx.x;
    const int bx = id % gm;
    const int by = (id / gm) % gn;
    const int bz = id / (gm * gn);
    const long tileM = (long)bx * 256;
    const long tileN = (long)by * 256;
    const bf16* Ab = A + tileM * lda + (long)bz * kcs;
    const bf16* Bb = Bt + tileN * ldb + (long)bz * kcs;

    const int wr = wid >> 2, wc = wid & 3;      // 2 x 4 waves
    const int l15 = lane & 15, kd = lane >> 4;
    const int swz = (lane & 7) << 4;

    f32x4 acc[8][4];
    #pragma unroll
    for (int m = 0; m < 8; ++m)
        #pragma unroll
        for (int n = 0; n < 4; ++n) { f32x4 z = {0.f,0.f,0.f,0.f}; acc[m][n] = z; }

    // staging: per matrix 32KB = 4 issues/thread of 16B
    auto STAGE_A = [&](int t) {
        const int buf = t & 1; const long kO = (long)t * 64;
        #pragma unroll
        for (int is = 0; is < 4; ++is) {
            const int o = is * 8192 + tid * 16;
            gload16(Ab + (long)(o >> 7) * lda + kO + ((o & 127) >> 1), lsA[buf] + o);
        }
    };
    auto STAGE_B = [&](int t) {
        const int buf = t & 1; const long kO = (long)t * 64;
        #pragma unroll
        for (int is = 0; is < 4; ++is) {
            const int o = is * 8192 + tid * 16;
            gload16(Bb + (long)(o >> 7) * ldb + kO + ((o & 127) >> 1), lsB[buf] + o);
        }
    };

#define RD_A(AV, HALF, AS) \
    _Pragma("unroll") for (int kk = 0; kk < 2; ++kk) \
    _Pragma("unroll") for (int m = 0; m < 4; ++m) \
        AV[kk][m] = *(const bf16x8*)((AS) + (((wr)*128 + (HALF)*64 + m*16 + l15) << 7) + ((kk*64 + kd*16) ^ swz));
#define RD_B(BV, NHALF, BS) \
    _Pragma("unroll") for (int kk = 0; kk < 2; ++kk) \
    _Pragma("unroll") for (int n = 0; n < 2; ++n) \
        BV[kk][n] = *(const bf16x8*)((BS) + (((wc)*64 + (NHALF)*32 + n*16 + l15) << 7) + ((kk*64 + kd*16) ^ swz));
#define PH_MFMA(MH, NHF, AV, BV) \
    _Pragma("unroll") for (int kk = 0; kk < 2; ++kk) \
    _Pragma("unroll") for (int m = 0; m < 4; ++m) \
    _Pragma("unroll") for (int n = 0; n < 2; ++n) \
        acc[(MH)*4+m][(NHF)*2+n] = __builtin_amdgcn_mfma_f32_16x16x32_bf16(AV[kk][m], BV[kk][n], acc[(MH)*4+m][(NHF)*2+n], 0, 0, 0);
#define SBAR __builtin_amdgcn_sched_barrier(0)

    const int NT = K >> 6;
    STAGE_A(0); STAGE_B(0);
    for (int t = 0; t < NT; ++t) {
        asm volatile("s_waitcnt vmcnt(0)" ::: "memory");
        __builtin_amdgcn_s_barrier();
        const unsigned char* As = lsA[t & 1];
        const unsigned char* Bs = lsB[t & 1];
        const bool st = (t + 1 < NT);
        // ---- phase 1: stage A(t+1) | read A-low + B-low | MFMA q(0,0)
        if (st) STAGE_A(t + 1);
        bf16x8 aL[2][4], bL[2][2];
        RD_A(aL, 0, As); RD_B(bL, 0, Bs);
        SBAR; __builtin_amdgcn_s_setprio(1);
        PH_MFMA(0, 0, aL, bL);
        __builtin_amdgcn_s_setprio(0); SBAR;
        // ---- phase 2: stage B(t+1) | read B-high | MFMA q(0,1)
        if (st) STAGE_B(t + 1);
        bf16x8 bH[2][2];
        RD_B(bH, 1, Bs);
        SBAR; __builtin_amdgcn_s_setprio(1);
        PH_MFMA(0, 1, aL, bH);
        __builtin_amdgcn_s_setprio(0); SBAR;
        // ---- phase 3: read A-high + B-low | MFMA q(1,0)
        bf16x8 aH[2][4], bL2[2][2];
        RD_A(aH, 1, As); RD_B(bL2, 0, Bs);
        SBAR; __builtin_amdgcn_s_setprio(1);
        PH_MFMA(1, 0, aH, bL2);
        __builtin_amdgcn_s_setprio(0); SBAR;
        // ---- phase 4: read B-high | MFMA q(1,1)
        bf16x8 bH2[2][2];
        RD_B(bH2, 1, Bs);
        SBAR; __builtin_amdgcn_s_setprio(1);
        PH_MFMA(1, 1, aH, bH2);
        __builtin_amdgcn_s_setprio(0); SBAR;
    }

    // epilogue: C/D layout col = lane&15, row = (lane>>4)*4 + j
    const long rowBase = tileM + wr * 128;
    const int  colBase = (int)tileN + wc * 64;
    #pragma unroll
    for (int m = 0; m < 8; ++m) {
        const long r0 = rowBase + m * 16 + (kd * 4);
        #pragma unroll
        for (int n = 0; n < 4; ++n) {
            const int col = colBase + n * 16 + l15;
            #pragma unroll
            for (int j = 0; j < 4; ++j) {
                const long tk = r0 + j;
                float v = acc[m][n][j];
                if constexpr (EPI == 0) {
                    v += bias[col] + aux1[(long)(tk >> 11) * DM + col];
                    v = gelu_f(v);
                    outH[tk * ldc + col] = (bf16)v;
                } else if constexpr (EPI == 1) {
                    v += bias[col];
                    v = gelu_f(v);
                    v *= aux1[tk * NH + (col >> 12)];
                    outH[tk * ldc + (col ^ (((int)tk & 7) << 3))] = (bf16)v;
                } else {
                    if (bz == 0) {
                        float bsum = 0.f;
                        #pragma unroll
                        for (int hh = 0; hh < NH; ++hh)
                            bsum += aux1[tk * NH + hh] * aux2[(long)hh * DM + col];
                        outF[tk * ldc + col] = v + bsum;
                    } else {
                        parts[(long)(bz - 1) * pStride + tk * ldc + col] = v;
                    }
                }
            }
        }
    }
#undef RD_A
#undef RD_B
#undef PH_MFMA
#undef SBAR
}

// ---------------- reduce: out += sum of np partials ----------------
__global__ __launch_bounds__(256) void k_red(float* __restrict__ out, const float* __restrict__ parts,
                                             long pStride, int np) {
    long i = ((long)blockIdx.x * 256 + threadIdx.x) * 4;
    float4 v = *(float4*)(out + i);
    #pragma unroll
    for (int p = 0; p < NKS - 1; ++p) {
        float4 q = *(const float4*)(parts + (long)p * pStride + i);
        v.x += q.x; v.y += q.y; v.z += q.z; v.w += q.w;
    }
    *(float4*)(out + i) = v;
    (void)np;
}

extern "C" void kernel_launch(void* const* d_in, const int* in_sizes, int n_in,
                              void* d_out, int out_size, void* d_ws, size_t ws_size,
                              hipStream_t stream)
{
    const float* x  = (const float*)d_in[0];
    const float* rs = (const float*)d_in[1];
    const float* W1 = (const float*)d_in[2];
    const float* b1 = (const float*)d_in[3];
    const float* W2 = (const float*)d_in[4];
    const float* b2 = (const float*)d_in[5];
    const float* Ws = (const float*)d_in[6];
    const float* bs = (const float*)d_in[7];
    const float* Wi = (const float*)d_in[8];
    const float* bi = (const float*)d_in[9];
    const float* Wg = (const float*)d_in[10];
    const float* bg = (const float*)d_in[11];

    float* out  = (float*)d_out;                    // [8192][1024] f32
    float* wout = out + (size_t)MT * DM;            // [8192][8]   f32 (output 1)

    unsigned char* ws = (unsigned char*)d_ws;
    size_t ofs = 0;
    auto alloc = [&](size_t bytes) { void* p = ws + ofs; ofs += (bytes + 255) & ~(size_t)255; return p; };

    bf16*  xbf  = (bf16*)alloc((size_t)MT * DM * 2);          // 16.8 MB (swizzled)
    bf16*  WiT  = (bf16*)alloc((size_t)DM * DM * 2);          //  2.1 MB (swizzled)
    bf16*  g    = (bf16*)alloc((size_t)MT * DM * 2);          // 16.8 MB (linear)
    float* sp   = (float*)alloc((size_t)NB * DM * 4);         // 16 KB
    bf16*  W1T  = (bf16*)alloc((size_t)NH * DF * DM * 2);     // 67.1 MB [hf][d] swizzled
    bf16*  W2T  = (bf16*)alloc((size_t)NH * DF * DM * 2);     // 67.1 MB [d][hf] swizzled
    bf16*  hp   = (bf16*)alloc((size_t)MQ * NH * DF * 2);     // 134.2 MB [t][hf] swizzled (per quarter)
    float* part = (float*)alloc((size_t)(NKS - 1) * MQ * DM * 4);  // 58.7 MB
    const long pStride = (long)MQ * DM;

    // stage 0: conversions / transposes / projections
    k_cvtx<<<(MT * DM) / (256 * 8), 256, 0, stream>>>(x, xbf);
    k_tcvt2<<<dim3(DM / 64, DM / 64, 1), 256, 0, stream>>>(Wi, WiT, DM, DM, 0, 0);
    k_sproj2<<<dim3(DM / 16, NB), 256, 0, stream>>>(rs, Ws, bs, sp);

    // stage 1: input proj -> gelu(combined) -> g, then gate weights
    k_g2<0><<<(MT / 256) * (DM / 256), 512, 0, stream>>>(
        xbf, DM, WiT, DM, DM, 0, MT / 256, DM / 256,
        g, nullptr, DM, bi, sp, nullptr, nullptr, 0);
    k_gate<<<MT / 4, 256, 0, stream>>>(g, Wg, bg, wout);

    // weight transposes
    k_tcvt2<<<dim3(DF / 64, DM / 64, NH), 256, 0, stream>>>(
        W1, W1T, DF, DM, (long)DM * DF, (long)DF * DM);
    k_tcvt2<<<dim3(DM / 64, DF / 64, NH), 256, 0, stream>>>(
        W2, W2T, DM, (long)NH * DF, (long)DF * DM, DF);

    // stage 2: per M-quarter: gemm1 (all heads) -> hp ; gemm2 (K-split 8) ; reduce
    for (int q = 0; q < MT / MQ; ++q) {
        const bf16*  xq = xbf + (size_t)q * MQ * DM;
        const float* wq = wout + (size_t)q * MQ * NH;
        float*       oq = out + (size_t)q * MQ * DM;
        k_g2<1><<<(MQ / 256) * (NH * DF / 256), 512, 0, stream>>>(
            xq, DM, W1T, DM, DM, 0, MQ / 256, NH * DF / 256,
            hp, nullptr, (long)NH * DF, b1, wq, nullptr, nullptr, 0);
        k_g2<2><<<(MQ / 256) * (DM / 256) * NKS, 512, 0, stream>>>(
            hp, (long)NH * DF, W2T, (long)NH * DF, KC, KC, MQ / 256, DM / 256,
            nullptr, oq, DM, nullptr, wq, b2, part, pStride);
        k_red<<<(MQ * DM) / (256 * 4), 256, 0, stream>>>(oq, part, pStride, NKS - 1);
    }
    (void)in_sizes; (void)n_in; (void)out_size;
}

// Round 6
// 1507.077 us; speedup vs baseline: 1.4895x; 1.0124x over previous
//
#include <hip/hip_runtime.h>
#include <hip/hip_bf16.h>
#include <math.h>

#define DM   1024
#define DF   4096
#define NH   8
#define NB   4
#define NS   2048
#define MT   (NB*NS)   // 8192 tokens
#define MQ   2048      // M-split quarter
#define KC   4096      // gemm2 K-split chunk
#define NKS  8         // gemm2 K-splits

typedef __bf16 bf16;
typedef __bf16 bf16x4 __attribute__((ext_vector_type(4)));
typedef __bf16 bf16x8 __attribute__((ext_vector_type(8)));
typedef float  f32x4  __attribute__((ext_vector_type(4)));

typedef __attribute__((address_space(3))) unsigned int u32_lds;
typedef const __attribute__((address_space(1))) void cv_glob;

__device__ __forceinline__ void gload16(const void* g, const void* l) {
    __builtin_amdgcn_global_load_lds(
        (cv_glob*)(unsigned long long)g,
        (u32_lds*)(unsigned int)(unsigned long long)l,
        16, 0, 0);
}

// tanh-form GELU: |gelu_tanh - gelu_erf| <= ~2e-3 absolute; 3x cheaper than erff.
__device__ __forceinline__ float gelu_f(float x) {
    float u = -1.5957691216057308f * fmaf(0.044715f * x, x * x, x);
    return x * __builtin_amdgcn_rcpf(1.f + __expf(u));
}

// SWIZZLE CONVENTION (T2, both-sides): every bf16 buffer consumed by GEMM staging is
// stored with 16B chunks permuted within each 128B (64-elem) row-block:
// elem e of row r stored at e ^ ((r&7)<<3). gload_lds copies linearly; ds_read
// XORs byte ^ ((row&7)<<4). Proven R2-R5: SQ_LDS_BANK_CONFLICT == 0.

// ---------------- x f32 -> bf16 (swizzled rows = tokens) ----------------
__global__ __launch_bounds__(256) void k_cvtx(const float* __restrict__ in, bf16* __restrict__ out) {
    long i = ((long)blockIdx.x * 256 + threadIdx.x) * 8;
    float4 a = *(const float4*)(in + i);
    float4 b = *(const float4*)(in + i + 4);
    bf16x8 o;
    o[0]=(bf16)a.x; o[1]=(bf16)a.y; o[2]=(bf16)a.z; o[3]=(bf16)a.w;
    o[4]=(bf16)b.x; o[5]=(bf16)b.y; o[6]=(bf16)b.z; o[7]=(bf16)b.w;
    long t7 = (i >> 10) & 7;
    *(bf16x8*)(out + (i ^ (t7 << 3))) = o;
}

// ---- transpose+convert+swizzle, 64x64 tile: out[c][r ^ ((c&7)<<3)] = (bf16)in[r*C+c] ----
__global__ __launch_bounds__(256) void k_tcvt2(const float* __restrict__ in, bf16* __restrict__ out,
                                               int C, long outStride, long inBatch, long outBatch) {
    __shared__ float t[64][65];
    const float* ip = in + (long)blockIdx.z * inBatch;
    bf16* op = out + (long)blockIdx.z * outBatch;
    const int c0 = blockIdx.x * 64, r0 = blockIdx.y * 64;
    const int tid = threadIdx.x;
    const int rr = tid >> 4, cc = tid & 15;
    #pragma unroll
    for (int it = 0; it < 4; ++it) {
        const int r = rr + 16 * it;
        float4 v = *(const float4*)(ip + (long)(r0 + r) * C + c0 + cc * 4);
        t[r][cc*4+0] = v.x; t[r][cc*4+1] = v.y; t[r][cc*4+2] = v.z; t[r][cc*4+3] = v.w;
    }
    __syncthreads();
    // write: 2 iters, each thread stores one 16B chunk (8 bf16) of an out-row
    #pragma unroll
    for (int it = 0; it < 2; ++it) {
        const int oc = (tid >> 3) + 32 * it;   // out row within tile (= source col)
        const int e0 = (tid & 7) * 8;          // elem chunk within out row (= source row - r0)
        bf16 tmp[8];
        #pragma unroll
        for (int j = 0; j < 8; ++j) tmp[j] = (bf16)t[e0 + j][oc];
        const int rs = e0 ^ ((oc & 7) << 3);   // swizzle flips bits 3..5 -> stays 16B-aligned
        *(bf16x8*)(op + (long)(c0 + oc) * outStride + r0 + rs) = *(bf16x8*)tmp;
    }
}

// ---------------- state projection (256 blocks): sp[b][d] = rs[b]@Ws[:,d] + bs[d] ----------------
__global__ __launch_bounds__(256) void k_sproj2(const float* __restrict__ rs, const float* __restrict__ Ws,
                                                const float* __restrict__ bs, float* __restrict__ sp) {
    const int d0 = blockIdx.x * 16;
    const int ks = threadIdx.x >> 4, dd = threadIdx.x & 15;
    const float* r = rs + blockIdx.y * DM;
    float acc = 0.f;
    #pragma unroll 4
    for (int k = ks * 64; k < ks * 64 + 64; ++k)
        acc += r[k] * Ws[(long)k * DM + d0 + dd];
    __shared__ float red[256];
    red[threadIdx.x] = acc;
    __syncthreads();
    if (threadIdx.x < 16) {
        float v = bs[d0 + threadIdx.x];
        #pragma unroll
        for (int s = 0; s < 16; ++s) v += red[threadIdx.x + 16 * s];
        sp[blockIdx.y * DM + d0 + threadIdx.x] = v;
    }
}

// ---------------- gate: logits = g@Wg + bg; softmax -> wout [t][8] ----------------
__global__ __launch_bounds__(256) void k_gate(const bf16* __restrict__ g, const float* __restrict__ Wg,
                                              const float* __restrict__ bg, float* __restrict__ wout) {
    int lane = threadIdx.x & 63, wid = threadIdx.x >> 6;
    long t = (long)blockIdx.x * 4 + wid;
    const bf16* gr = g + t * DM + lane * 16;
    bf16x8 v0 = *(const bf16x8*)gr;
    bf16x8 v1 = *(const bf16x8*)(gr + 8);
    float s0=0,s1=0,s2=0,s3=0,s4=0,s5=0,s6=0,s7=0;
    #pragma unroll
    for (int i = 0; i < 16; ++i) {
        float gv = (float)((i < 8) ? v0[i] : v1[i - 8]);
        const float4* wr = (const float4*)(Wg + (long)(lane * 16 + i) * NH);
        float4 wa = wr[0], wb = wr[1];
        s0 += gv*wa.x; s1 += gv*wa.y; s2 += gv*wa.z; s3 += gv*wa.w;
        s4 += gv*wb.x; s5 += gv*wb.y; s6 += gv*wb.z; s7 += gv*wb.w;
    }
    #pragma unroll
    for (int off = 32; off >= 1; off >>= 1) {
        s0 += __shfl_xor(s0, off); s1 += __shfl_xor(s1, off);
        s2 += __shfl_xor(s2, off); s3 += __shfl_xor(s3, off);
        s4 += __shfl_xor(s4, off); s5 += __shfl_xor(s5, off);
        s6 += __shfl_xor(s6, off); s7 += __shfl_xor(s7, off);
    }
    float l0=s0+bg[0], l1=s1+bg[1], l2=s2+bg[2], l3=s3+bg[3];
    float l4=s4+bg[4], l5=s5+bg[5], l6=s6+bg[6], l7=s7+bg[7];
    float m = fmaxf(fmaxf(fmaxf(l0,l1),fmaxf(l2,l3)), fmaxf(fmaxf(l4,l5),fmaxf(l6,l7)));
    float e0=expf(l0-m), e1=expf(l1-m), e2=expf(l2-m), e3=expf(l3-m);
    float e4=expf(l4-m), e5=expf(l5-m), e6=expf(l6-m), e7=expf(l7-m);
    float inv = 1.f / (e0+e1+e2+e3+e4+e5+e6+e7);
    if (lane == 0) {
        float* wo = wout + t * NH;
        wo[0]=e0*inv; wo[1]=e1*inv; wo[2]=e2*inv; wo[3]=e3*inv;
        wo[4]=e4*inv; wo[5]=e5*inv; wo[6]=e6*inv; wo[7]=e7*inv;
    }
}

// ============ 256x256x64 bf16 GEMM, 4-phase interleave + 3-deep A / 2-deep B pipeline ============
// 8 waves (2M x 4N), wave out 128x64, acc 8x4 f32x4. LDS: A 3x32K + B 2x32K = 160 KB.
// Per thread per tile: A 4 + B 4 gload16. Schedule (iter t):
//   ph1: issue STAGE_B(t+1) | ds_read A-low,B-low | 16 MFMA q(0,0)
//   ph2: issue STAGE_A(t+2) | ds_read B-high      | 16 MFMA q(0,1)
//   ph3:                      ds_read A-high,B-low| 16 MFMA q(1,0)
//   ph4:                      ds_read B-high      | 16 MFMA q(1,1)
//   end: s_waitcnt vmcnt(4)  (retires A(t+1),B(t+1) in issue order; A(t+2) stays in flight)
//        s_barrier            -> tile t+1 collectively resident. Never drains to 0 mid-loop.
// WAR-safe: any buffer written by STAGE_X was last read >=1 barrier earlier.
// EPI 0: gelu(acc+bias[col]+sp[t>>11][col])        -> bf16 outH (unswizzled)
// EPI 1: w[t][col>>12]*gelu(acc+bias[col])         -> bf16 outH (swizzled)
// EPI 2: bz==0: acc+sum_h w*b2 -> outF ; bz>0: acc -> parts[bz-1]
template<int EPI>
__global__ __launch_bounds__(512, 2) void k_g2(
    const bf16* __restrict__ A, long lda,
    const bf16* __restrict__ Bt, long ldb,
    int K, long kcs, int gm, int gn,
    bf16* __restrict__ outH, float* __restrict__ outF, long ldc,
    const float* __restrict__ bias,
    const float* __restrict__ aux1, const float* __restrict__ aux2,
    float* __restrict__ parts, long pStride)
{
    __shared__ __align__(16) unsigned char lsA[3][32 * 1024];
    __shared__ __align__(16) unsigned char lsB[2][32 * 1024];
    const int tid = threadIdx.x, lane = tid & 63, wid = tid >> 6;

    const int id = blockIdx.x;
    const int bx = id % gm;
    const int by = (id / gm) % gn;
    const int bz = id / (gm * gn);
    const long tileM = (long)bx * 256;
    const long tileN = (long)by * 256;
    const bf16* Ab = A + tileM * lda + (long)bz * kcs;
    const bf16* Bb = Bt + tileN * ldb + (long)bz * kcs;

    const int wr = wid >> 2, wc = wid & 3;      // 2 x 4 waves
    const int l15 = lane & 15, kd = lane >> 4;
    const int swz = (lane & 7) << 4;

    f32x4 acc[8][4];
    #pragma unroll
    for (int m = 0; m < 8; ++m)
        #pragma unroll
        for (int n = 0; n < 4; ++n) { f32x4 z = {0.f,0.f,0.f,0.f}; acc[m][n] = z; }

    auto STAGE_A = [&](int t) {
        const int buf = t % 3; const long kO = (long)t * 64;
        #pragma unroll
        for (int is = 0; is < 4; ++is) {
            const int o = is * 8192 + tid * 16;
            gload16(Ab + (long)(o >> 7) * lda + kO + ((o & 127) >> 1), lsA[buf] + o);
        }
    };
    auto STAGE_B = [&](int t) {
        const int buf = t & 1; const long kO = (long)t * 64;
        #pragma unroll
        for (int is = 0; is < 4; ++is) {
            const int o = is * 8192 + tid * 16;
            gload16(Bb + (long)(o >> 7) * ldb + kO + ((o & 127) >> 1), lsB[buf] + o);
        }
    };

#define RD_A(AV, HALF, AS) \
    _Pragma("unroll") for (int kk = 0; kk < 2; ++kk) \
    _Pragma("unroll") for (int m = 0; m < 4; ++m) \
        AV[kk][m] = *(const bf16x8*)((AS) + (((wr)*128 + (HALF)*64 + m*16 + l15) << 7) + ((kk*64 + kd*16) ^ swz));
#define RD_B(BV, NHALF, BS) \
    _Pragma("unroll") for (int kk = 0; kk < 2; ++kk) \
    _Pragma("unroll") for (int n = 0; n < 2; ++n) \
        BV[kk][n] = *(const bf16x8*)((BS) + (((wc)*64 + (NHALF)*32 + n*16 + l15) << 7) + ((kk*64 + kd*16) ^ swz));
#define PH_MFMA(MH, NHF, AV, BV) \
    _Pragma("unroll") for (int kk = 0; kk < 2; ++kk) \
    _Pragma("unroll") for (int m = 0; m < 4; ++m) \
    _Pragma("unroll") for (int n = 0; n < 2; ++n) \
        acc[(MH)*4+m][(NHF)*2+n] = __builtin_amdgcn_mfma_f32_16x16x32_bf16(AV[kk][m], BV[kk][n], acc[(MH)*4+m][(NHF)*2+n], 0, 0, 0);
#define SBAR __builtin_amdgcn_sched_barrier(0)

    const int NT = K >> 6;                      // >= 16 at all call sites
    // prologue: prime A(0),B(0),A(1); make tile 0 resident, keep A(1) in flight
    STAGE_A(0); STAGE_B(0); STAGE_A(1);
    asm volatile("s_waitcnt vmcnt(4)" ::: "memory");
    __builtin_amdgcn_s_barrier();
    SBAR;
    for (int t = 0; t < NT; ++t) {
        const unsigned char* As = lsA[t % 3];
        const unsigned char* Bs = lsB[t & 1];
        // ---- phase 1: stage B(t+1) | read A-low + B-low | MFMA q(0,0)
        if (t + 1 < NT) STAGE_B(t + 1);
        bf16x8 aL[2][4], bL[2][2];
        RD_A(aL, 0, As); RD_B(bL, 0, Bs);
        SBAR; __builtin_amdgcn_s_setprio(1);
        PH_MFMA(0, 0, aL, bL);
        __builtin_amdgcn_s_setprio(0); SBAR;
        // ---- phase 2: stage A(t+2) | read B-high | MFMA q(0,1)
        if (t + 2 < NT) STAGE_A(t + 2);
        bf16x8 bH[2][2];
        RD_B(bH, 1, Bs);
        SBAR; __builtin_amdgcn_s_setprio(1);
        PH_MFMA(0, 1, aL, bH);
        __builtin_amdgcn_s_setprio(0); SBAR;
        // ---- phase 3: read A-high + B-low | MFMA q(1,0)
        bf16x8 aH[2][4], bL2[2][2];
        RD_A(aH, 1, As); RD_B(bL2, 0, Bs);
        SBAR; __builtin_amdgcn_s_setprio(1);
        PH_MFMA(1, 0, aH, bL2);
        __builtin_amdgcn_s_setprio(0); SBAR;
        // ---- phase 4: read B-high | MFMA q(1,1)
        bf16x8 bH2[2][2];
        RD_B(bH2, 1, Bs);
        SBAR; __builtin_amdgcn_s_setprio(1);
        PH_MFMA(1, 1, aH, bH2);
        __builtin_amdgcn_s_setprio(0); SBAR;
        // ---- end of tile: make t+1 resident; keep A(t+2) in flight
        if (t + 2 < NT) {
            asm volatile("s_waitcnt vmcnt(4)" ::: "memory");
            __builtin_amdgcn_s_barrier();
            SBAR;
        } else if (t + 1 < NT) {
            asm volatile("s_waitcnt vmcnt(0)" ::: "memory");
            __builtin_amdgcn_s_barrier();
            SBAR;
        }
    }

    // epilogue: C/D layout col = lane&15, row = (lane>>4)*4 + j
    const long rowBase = tileM + wr * 128;
    const int  colBase = (int)tileN + wc * 64;
    #pragma unroll
    for (int m = 0; m < 8; ++m) {
        const long r0 = rowBase + m * 16 + (kd * 4);
        #pragma unroll
        for (int n = 0; n < 4; ++n) {
            const int col = colBase + n * 16 + l15;
            #pragma unroll
            for (int j = 0; j < 4; ++j) {
                const long tk = r0 + j;
                float v = acc[m][n][j];
                if constexpr (EPI == 0) {
                    v += bias[col] + aux1[(long)(tk >> 11) * DM + col];
                    v = gelu_f(v);
                    outH[tk * ldc + col] = (bf16)v;
                } else if constexpr (EPI == 1) {
                    v += bias[col];
                    v = gelu_f(v);
                    v *= aux1[tk * NH + (col >> 12)];
                    outH[tk * ldc + (col ^ (((int)tk & 7) << 3))] = (bf16)v;
                } else {
                    if (bz == 0) {
                        float bsum = 0.f;
                        #pragma unroll
                        for (int hh = 0; hh < NH; ++hh)
                            bsum += aux1[tk * NH + hh] * aux2[(long)hh * DM + col];
                        outF[tk * ldc + col] = v + bsum;
                    } else {
                        parts[(long)(bz - 1) * pStride + tk * ldc + col] = v;
                    }
                }
            }
        }
    }
#undef RD_A
#undef RD_B
#undef PH_MFMA
#undef SBAR
}

// ---------------- reduce: out += sum of partials ----------------
__global__ __launch_bounds__(256) void k_red(float* __restrict__ out, const float* __restrict__ parts,
                                             long pStride, int np) {
    long i = ((long)blockIdx.x * 256 + threadIdx.x) * 4;
    float4 v = *(float4*)(out + i);
    #pragma unroll
    for (int p = 0; p < NKS - 1; ++p) {
        float4 q = *(const float4*)(parts + (long)p * pStride + i);
        v.x += q.x; v.y += q.y; v.z += q.z; v.w += q.w;
    }
    *(float4*)(out + i) = v;
    (void)np;
}

extern "C" void kernel_launch(void* const* d_in, const int* in_sizes, int n_in,
                              void* d_out, int out_size, void* d_ws, size_t ws_size,
                              hipStream_t stream)
{
    const float* x  = (const float*)d_in[0];
    const float* rs = (const float*)d_in[1];
    const float* W1 = (const float*)d_in[2];
    const float* b1 = (const float*)d_in[3];
    const float* W2 = (const float*)d_in[4];
    const float* b2 = (const float*)d_in[5];
    const float* Ws = (const float*)d_in[6];
    const float* bs = (const float*)d_in[7];
    const float* Wi = (const float*)d_in[8];
    const float* bi = (const float*)d_in[9];
    const float* Wg = (const float*)d_in[10];
    const float* bg = (const float*)d_in[11];

    float* out  = (float*)d_out;                    // [8192][1024] f32
    float* wout = out + (size_t)MT * DM;            // [8192][8]   f32 (output 1)

    unsigned char* ws = (unsigned char*)d_ws;
    size_t ofs = 0;
    auto alloc = [&](size_t bytes) { void* p = ws + ofs; ofs += (bytes + 255) & ~(size_t)255; return p; };

    bf16*  xbf  = (bf16*)alloc((size_t)MT * DM * 2);          // 16.8 MB (swizzled)
    bf16*  WiT  = (bf16*)alloc((size_t)DM * DM * 2);          //  2.1 MB (swizzled)
    bf16*  g    = (bf16*)alloc((size_t)MT * DM * 2);          // 16.8 MB (linear)
    float* sp   = (float*)alloc((size_t)NB * DM * 4);         // 16 KB
    bf16*  W1T  = (bf16*)alloc((size_t)NH * DF * DM * 2);     // 67.1 MB [hf][d] swizzled
    bf16*  W2T  = (bf16*)alloc((size_t)NH * DF * DM * 2);     // 67.1 MB [d][hf] swizzled
    bf16*  hp   = (bf16*)alloc((size_t)MQ * NH * DF * 2);     // 134.2 MB [t][hf] swizzled (per quarter)
    float* part = (float*)alloc((size_t)(NKS - 1) * MQ * DM * 4);  // 58.7 MB
    const long pStride = (long)MQ * DM;

    // stage 0: conversions / transposes / projections
    k_cvtx<<<(MT * DM) / (256 * 8), 256, 0, stream>>>(x, xbf);
    k_tcvt2<<<dim3(DM / 64, DM / 64, 1), 256, 0, stream>>>(Wi, WiT, DM, DM, 0, 0);
    k_sproj2<<<dim3(DM / 16, NB), 256, 0, stream>>>(rs, Ws, bs, sp);

    // stage 1: input proj -> gelu(combined) -> g, then gate weights
    k_g2<0><<<(MT / 256) * (DM / 256), 512, 0, stream>>>(
        xbf, DM, WiT, DM, DM, 0, MT / 256, DM / 256,
        g, nullptr, DM, bi, sp, nullptr, nullptr, 0);
    k_gate<<<MT / 4, 256, 0, stream>>>(g, Wg, bg, wout);

    // weight transposes
    k_tcvt2<<<dim3(DF / 64, DM / 64, NH), 256, 0, stream>>>(
        W1, W1T, DF, DM, (long)DM * DF, (long)DF * DM);
    k_tcvt2<<<dim3(DM / 64, DF / 64, NH), 256, 0, stream>>>(
        W2, W2T, DM, (long)NH * DF, (long)DF * DM, DF);

    // stage 2: per M-quarter: gemm1 (all heads) -> hp ; gemm2 (K-split 8) ; reduce
    for (int q = 0; q < MT / MQ; ++q) {
        const bf16*  xq = xbf + (size_t)q * MQ * DM;
        const float* wq = wout + (size_t)q * MQ * NH;
        float*       oq = out + (size_t)q * MQ * DM;
        k_g2<1><<<(MQ / 256) * (NH * DF / 256), 512, 0, stream>>>(
            xq, DM, W1T, DM, DM, 0, MQ / 256, NH * DF / 256,
            hp, nullptr, (long)NH * DF, b1, wq, nullptr, nullptr, 0);
        k_g2<2><<<(MQ / 256) * (DM / 256) * NKS, 512, 0, stream>>>(
            hp, (long)NH * DF, W2T, (long)NH * DF, KC, KC, MQ / 256, DM / 256,
            nullptr, oq, DM, nullptr, wq, b2, part, pStride);
        k_red<<<(MQ * DM) / (256 * 4), 256, 0, stream>>>(oq, part, pStride, NKS - 1);
    }
    (void)in_sizes; (void)n_in; (void)out_size;
}

// Round 7
// 1481.184 us; speedup vs baseline: 1.5155x; 1.0175x over previous
//
#include <hip/hip_runtime.h>
#include <hip/hip_bf16.h>
#include <math.h>

#define DM   1024
#define DF   4096
#define NH   8
#define NB   4
#define NS   2048
#define MT   (NB*NS)   // 8192 tokens
#define MQ   2048      // M-split quarter
#define KC   4096      // gemm2 K-split chunk
#define NKS  8         // gemm2 K-splits

typedef __bf16 bf16;
typedef __bf16 bf16x4 __attribute__((ext_vector_type(4)));
typedef __bf16 bf16x8 __attribute__((ext_vector_type(8)));
typedef float  f32x4  __attribute__((ext_vector_type(4)));

typedef __attribute__((address_space(3))) unsigned int u32_lds;
typedef const __attribute__((address_space(1))) void cv_glob;

__device__ __forceinline__ void gload16(const void* g, const void* l) {
    __builtin_amdgcn_global_load_lds(
        (cv_glob*)(unsigned long long)g,
        (u32_lds*)(unsigned int)(unsigned long long)l,
        16, 0, 0);
}

// tanh-form GELU: |gelu_tanh - gelu_erf| <= ~2e-3 absolute; 3x cheaper than erff.
__device__ __forceinline__ float gelu_f(float x) {
    float u = -1.5957691216057308f * fmaf(0.044715f * x, x * x, x);
    return x * __builtin_amdgcn_rcpf(1.f + __expf(u));
}

// SWIZZLE CONVENTION (T2, both-sides): every bf16 buffer consumed by GEMM staging is
// stored with 16B chunks permuted within each 128B (64-elem) row-block:
// elem e of row r stored at e ^ ((r&7)<<3). gload_lds copies linearly; ds_read
// XORs byte ^ ((row&7)<<4). Proven R2-R6: SQ_LDS_BANK_CONFLICT == 0.

// ---------------- x f32 -> bf16 (swizzled rows = tokens) ----------------
__global__ __launch_bounds__(256) void k_cvtx(const float* __restrict__ in, bf16* __restrict__ out) {
    long i = ((long)blockIdx.x * 256 + threadIdx.x) * 8;
    float4 a = *(const float4*)(in + i);
    float4 b = *(const float4*)(in + i + 4);
    bf16x8 o;
    o[0]=(bf16)a.x; o[1]=(bf16)a.y; o[2]=(bf16)a.z; o[3]=(bf16)a.w;
    o[4]=(bf16)b.x; o[5]=(bf16)b.y; o[6]=(bf16)b.z; o[7]=(bf16)b.w;
    long t7 = (i >> 10) & 7;
    *(bf16x8*)(out + (i ^ (t7 << 3))) = o;
}

// ---- transpose+convert+swizzle, 64x64 tile: out[c][r ^ ((c&7)<<3)] = (bf16)in[r*C+c] ----
__global__ __launch_bounds__(256) void k_tcvt2(const float* __restrict__ in, bf16* __restrict__ out,
                                               int C, long outStride, long inBatch, long outBatch) {
    __shared__ float t[64][65];
    const float* ip = in + (long)blockIdx.z * inBatch;
    bf16* op = out + (long)blockIdx.z * outBatch;
    const int c0 = blockIdx.x * 64, r0 = blockIdx.y * 64;
    const int tid = threadIdx.x;
    const int rr = tid >> 4, cc = tid & 15;
    #pragma unroll
    for (int it = 0; it < 4; ++it) {
        const int r = rr + 16 * it;
        float4 v = *(const float4*)(ip + (long)(r0 + r) * C + c0 + cc * 4);
        t[r][cc*4+0] = v.x; t[r][cc*4+1] = v.y; t[r][cc*4+2] = v.z; t[r][cc*4+3] = v.w;
    }
    __syncthreads();
    #pragma unroll
    for (int it = 0; it < 2; ++it) {
        const int oc = (tid >> 3) + 32 * it;   // out row within tile (= source col)
        const int e0 = (tid & 7) * 8;          // elem chunk within out row (= source row - r0)
        bf16 tmp[8];
        #pragma unroll
        for (int j = 0; j < 8; ++j) tmp[j] = (bf16)t[e0 + j][oc];
        const int rs = e0 ^ ((oc & 7) << 3);   // swizzle flips bits 3..5 -> stays 16B-aligned
        *(bf16x8*)(op + (long)(c0 + oc) * outStride + r0 + rs) = *(bf16x8*)tmp;
    }
}

// ---------------- state projection (256 blocks): sp[b][d] = rs[b]@Ws[:,d] + bs[d] ----------------
__global__ __launch_bounds__(256) void k_sproj2(const float* __restrict__ rs, const float* __restrict__ Ws,
                                                const float* __restrict__ bs, float* __restrict__ sp) {
    const int d0 = blockIdx.x * 16;
    const int ks = threadIdx.x >> 4, dd = threadIdx.x & 15;
    const float* r = rs + blockIdx.y * DM;
    float acc = 0.f;
    #pragma unroll 4
    for (int k = ks * 64; k < ks * 64 + 64; ++k)
        acc += r[k] * Ws[(long)k * DM + d0 + dd];
    __shared__ float red[256];
    red[threadIdx.x] = acc;
    __syncthreads();
    if (threadIdx.x < 16) {
        float v = bs[d0 + threadIdx.x];
        #pragma unroll
        for (int s = 0; s < 16; ++s) v += red[threadIdx.x + 16 * s];
        sp[blockIdx.y * DM + d0 + threadIdx.x] = v;
    }
}

// ---------------- gate: logits = g@Wg + bg; softmax -> wout [t][8] ----------------
__global__ __launch_bounds__(256) void k_gate(const bf16* __restrict__ g, const float* __restrict__ Wg,
                                              const float* __restrict__ bg, float* __restrict__ wout) {
    int lane = threadIdx.x & 63, wid = threadIdx.x >> 6;
    long t = (long)blockIdx.x * 4 + wid;
    const bf16* gr = g + t * DM + lane * 16;
    bf16x8 v0 = *(const bf16x8*)gr;
    bf16x8 v1 = *(const bf16x8*)(gr + 8);
    float s0=0,s1=0,s2=0,s3=0,s4=0,s5=0,s6=0,s7=0;
    #pragma unroll
    for (int i = 0; i < 16; ++i) {
        float gv = (float)((i < 8) ? v0[i] : v1[i - 8]);
        const float4* wr = (const float4*)(Wg + (long)(lane * 16 + i) * NH);
        float4 wa = wr[0], wb = wr[1];
        s0 += gv*wa.x; s1 += gv*wa.y; s2 += gv*wa.z; s3 += gv*wa.w;
        s4 += gv*wb.x; s5 += gv*wb.y; s6 += gv*wb.z; s7 += gv*wb.w;
    }
    #pragma unroll
    for (int off = 32; off >= 1; off >>= 1) {
        s0 += __shfl_xor(s0, off); s1 += __shfl_xor(s1, off);
        s2 += __shfl_xor(s2, off); s3 += __shfl_xor(s3, off);
        s4 += __shfl_xor(s4, off); s5 += __shfl_xor(s5, off);
        s6 += __shfl_xor(s6, off); s7 += __shfl_xor(s7, off);
    }
    float l0=s0+bg[0], l1=s1+bg[1], l2=s2+bg[2], l3=s3+bg[3];
    float l4=s4+bg[4], l5=s5+bg[5], l6=s6+bg[6], l7=s7+bg[7];
    float m = fmaxf(fmaxf(fmaxf(l0,l1),fmaxf(l2,l3)), fmaxf(fmaxf(l4,l5),fmaxf(l6,l7)));
    float e0=expf(l0-m), e1=expf(l1-m), e2=expf(l2-m), e3=expf(l3-m);
    float e4=expf(l4-m), e5=expf(l5-m), e6=expf(l6-m), e7=expf(l7-m);
    float inv = 1.f / (e0+e1+e2+e3+e4+e5+e6+e7);
    if (lane == 0) {
        float* wo = wout + t * NH;
        wo[0]=e0*inv; wo[1]=e1*inv; wo[2]=e2*inv; wo[3]=e3*inv;
        wo[4]=e4*inv; wo[5]=e5*inv; wo[6]=e6*inv; wo[7]=e7*inv;
    }
}

// ============ 256x256x64 bf16 GEMM, 4-phase interleave + 3-deep A / 2-deep B pipeline ============
// Identical schedule to R6 (proven correct). New: MAP — co-residency-aware block mapping.
// All blocks of a launch-wave are simultaneously resident (1 block/CU); XCD = id % 8
// (round-robin). MAP makes each XCD's 32 concurrent blocks share staging slices so the
// per-K-step active set (12 x 32KB = 384 KB) lives in its private L2:
//   MAP 0: natural bx-fastest (small grids / L2-resident B).
//   MAP 1: gemm1 (grid 8x128, 4 rounds of 256): XCD x works a 4bx x 8by rectangle.
//   MAP 2: gemm2 (grid 8x4x8): bz (K-chunk) = id%8 -> one hp/W2T K-chunk per XCD;
//          bx,by sweep within the XCD -> A re-served x4, B x8 from L2; HBM ~ compulsory.
// EPI 0: gelu(acc+bias[col]+sp[t>>11][col])        -> bf16 outH (unswizzled)
// EPI 1: w[t][col>>12]*gelu(acc+bias[col])         -> bf16 outH (swizzled)
// EPI 2: bz==0: acc+sum_h w*b2 -> outF ; bz>0: acc -> parts[bz-1]
template<int EPI, int MAP>
__global__ __launch_bounds__(512, 2) void k_g2(
    const bf16* __restrict__ A, long lda,
    const bf16* __restrict__ Bt, long ldb,
    int K, long kcs, int gm, int gn,
    bf16* __restrict__ outH, float* __restrict__ outF, long ldc,
    const float* __restrict__ bias,
    const float* __restrict__ aux1, const float* __restrict__ aux2,
    float* __restrict__ parts, long pStride)
{
    __shared__ __align__(16) unsigned char lsA[3][32 * 1024];
    __shared__ __align__(16) unsigned char lsB[2][32 * 1024];
    const int tid = threadIdx.x, lane = tid & 63, wid = tid >> 6;

    const int id = blockIdx.x;
    int bx, by, bz;
    if (MAP == 1) {            // grid 1024 = 8bx x 128by, rounds of 256
        const int x = id & 7, j = (id >> 3) & 31, r = id >> 8;
        bx = (x & 1) * 4 + (j & 3);
        by = (x >> 1) * 8 + (j >> 2) + r * 32;
        bz = 0;
    } else if (MAP == 2) {     // grid 256 = 8bx x 4by x 8bz
        bz = id & 7;
        bx = (id >> 3) & 7;
        by = id >> 6;
    } else {
        bx = id % gm; by = (id / gm) % gn; bz = id / (gm * gn);
    }
    const long tileM = (long)bx * 256;
    const long tileN = (long)by * 256;
    const bf16* Ab = A + tileM * lda + (long)bz * kcs;
    const bf16* Bb = Bt + tileN * ldb + (long)bz * kcs;

    const int wr = wid >> 2, wc = wid & 3;      // 2 x 4 waves
    const int l15 = lane & 15, kd = lane >> 4;
    const int swz = (lane & 7) << 4;

    f32x4 acc[8][4];
    #pragma unroll
    for (int m = 0; m < 8; ++m)
        #pragma unroll
        for (int n = 0; n < 4; ++n) { f32x4 z = {0.f,0.f,0.f,0.f}; acc[m][n] = z; }

    auto STAGE_A = [&](int t) {
        const int buf = t % 3; const long kO = (long)t * 64;
        #pragma unroll
        for (int is = 0; is < 4; ++is) {
            const int o = is * 8192 + tid * 16;
            gload16(Ab + (long)(o >> 7) * lda + kO + ((o & 127) >> 1), lsA[buf] + o);
        }
    };
    auto STAGE_B = [&](int t) {
        const int buf = t & 1; const long kO = (long)t * 64;
        #pragma unroll
        for (int is = 0; is < 4; ++is) {
            const int o = is * 8192 + tid * 16;
            gload16(Bb + (long)(o >> 7) * ldb + kO + ((o & 127) >> 1), lsB[buf] + o);
        }
    };

#define RD_A(AV, HALF, AS) \
    _Pragma("unroll") for (int kk = 0; kk < 2; ++kk) \
    _Pragma("unroll") for (int m = 0; m < 4; ++m) \
        AV[kk][m] = *(const bf16x8*)((AS) + (((wr)*128 + (HALF)*64 + m*16 + l15) << 7) + ((kk*64 + kd*16) ^ swz));
#define RD_B(BV, NHALF, BS) \
    _Pragma("unroll") for (int kk = 0; kk < 2; ++kk) \
    _Pragma("unroll") for (int n = 0; n < 2; ++n) \
        BV[kk][n] = *(const bf16x8*)((BS) + (((wc)*64 + (NHALF)*32 + n*16 + l15) << 7) + ((kk*64 + kd*16) ^ swz));
#define PH_MFMA(MH, NHF, AV, BV) \
    _Pragma("unroll") for (int kk = 0; kk < 2; ++kk) \
    _Pragma("unroll") for (int m = 0; m < 4; ++m) \
    _Pragma("unroll") for (int n = 0; n < 2; ++n) \
        acc[(MH)*4+m][(NHF)*2+n] = __builtin_amdgcn_mfma_f32_16x16x32_bf16(AV[kk][m], BV[kk][n], acc[(MH)*4+m][(NHF)*2+n], 0, 0, 0);
#define SBAR __builtin_amdgcn_sched_barrier(0)

    const int NT = K >> 6;                      // >= 16 at all call sites
    STAGE_A(0); STAGE_B(0); STAGE_A(1);
    asm volatile("s_waitcnt vmcnt(4)" ::: "memory");
    __builtin_amdgcn_s_barrier();
    SBAR;
    for (int t = 0; t < NT; ++t) {
        const unsigned char* As = lsA[t % 3];
        const unsigned char* Bs = lsB[t & 1];
        // ---- phase 1: stage B(t+1) | read A-low + B-low | MFMA q(0,0)
        if (t + 1 < NT) STAGE_B(t + 1);
        bf16x8 aL[2][4], bL[2][2];
        RD_A(aL, 0, As); RD_B(bL, 0, Bs);
        SBAR; __builtin_amdgcn_s_setprio(1);
        PH_MFMA(0, 0, aL, bL);
        __builtin_amdgcn_s_setprio(0); SBAR;
        // ---- phase 2: stage A(t+2) | read B-high | MFMA q(0,1)
        if (t + 2 < NT) STAGE_A(t + 2);
        bf16x8 bH[2][2];
        RD_B(bH, 1, Bs);
        SBAR; __builtin_amdgcn_s_setprio(1);
        PH_MFMA(0, 1, aL, bH);
        __builtin_amdgcn_s_setprio(0); SBAR;
        // ---- phase 3: read A-high + B-low | MFMA q(1,0)
        bf16x8 aH[2][4], bL2[2][2];
        RD_A(aH, 1, As); RD_B(bL2, 0, Bs);
        SBAR; __builtin_amdgcn_s_setprio(1);
        PH_MFMA(1, 0, aH, bL2);
        __builtin_amdgcn_s_setprio(0); SBAR;
        // ---- phase 4: read B-high | MFMA q(1,1)
        bf16x8 bH2[2][2];
        RD_B(bH2, 1, Bs);
        SBAR; __builtin_amdgcn_s_setprio(1);
        PH_MFMA(1, 1, aH, bH2);
        __builtin_amdgcn_s_setprio(0); SBAR;
        // ---- end of tile: make t+1 resident; keep A(t+2) in flight
        if (t + 2 < NT) {
            asm volatile("s_waitcnt vmcnt(4)" ::: "memory");
            __builtin_amdgcn_s_barrier();
            SBAR;
        } else if (t + 1 < NT) {
            asm volatile("s_waitcnt vmcnt(0)" ::: "memory");
            __builtin_amdgcn_s_barrier();
            SBAR;
        }
    }

    // epilogue: C/D layout col = lane&15, row = (lane>>4)*4 + j
    const long rowBase = tileM + wr * 128;
    const int  colBase = (int)tileN + wc * 64;
    #pragma unroll
    for (int m = 0; m < 8; ++m) {
        const long r0 = rowBase + m * 16 + (kd * 4);
        #pragma unroll
        for (int n = 0; n < 4; ++n) {
            const int col = colBase + n * 16 + l15;
            #pragma unroll
            for (int j = 0; j < 4; ++j) {
                const long tk = r0 + j;
                float v = acc[m][n][j];
                if constexpr (EPI == 0) {
                    v += bias[col] + aux1[(long)(tk >> 11) * DM + col];
                    v = gelu_f(v);
                    outH[tk * ldc + col] = (bf16)v;
                } else if constexpr (EPI == 1) {
                    v += bias[col];
                    v = gelu_f(v);
                    v *= aux1[tk * NH + (col >> 12)];
                    outH[tk * ldc + (col ^ (((int)tk & 7) << 3))] = (bf16)v;
                } else {
                    if (bz == 0) {
                        float bsum = 0.f;
                        #pragma unroll
                        for (int hh = 0; hh < NH; ++hh)
                            bsum += aux1[tk * NH + hh] * aux2[(long)hh * DM + col];
                        outF[tk * ldc + col] = v + bsum;
                    } else {
                        parts[(long)(bz - 1) * pStride + tk * ldc + col] = v;
                    }
                }
            }
        }
    }
#undef RD_A
#undef RD_B
#undef PH_MFMA
#undef SBAR
}

// ---------------- reduce: out += sum of partials ----------------
__global__ __launch_bounds__(256) void k_red(float* __restrict__ out, const float* __restrict__ parts,
                                             long pStride, int np) {
    long i = ((long)blockIdx.x * 256 + threadIdx.x) * 4;
    float4 v = *(float4*)(out + i);
    #pragma unroll
    for (int p = 0; p < NKS - 1; ++p) {
        float4 q = *(const float4*)(parts + (long)p * pStride + i);
        v.x += q.x; v.y += q.y; v.z += q.z; v.w += q.w;
    }
    *(float4*)(out + i) = v;
    (void)np;
}

extern "C" void kernel_launch(void* const* d_in, const int* in_sizes, int n_in,
                              void* d_out, int out_size, void* d_ws, size_t ws_size,
                              hipStream_t stream)
{
    const float* x  = (const float*)d_in[0];
    const float* rs = (const float*)d_in[1];
    const float* W1 = (const float*)d_in[2];
    const float* b1 = (const float*)d_in[3];
    const float* W2 = (const float*)d_in[4];
    const float* b2 = (const float*)d_in[5];
    const float* Ws = (const float*)d_in[6];
    const float* bs = (const float*)d_in[7];
    const float* Wi = (const float*)d_in[8];
    const float* bi = (const float*)d_in[9];
    const float* Wg = (const float*)d_in[10];
    const float* bg = (const float*)d_in[11];

    float* out  = (float*)d_out;                    // [8192][1024] f32
    float* wout = out + (size_t)MT * DM;            // [8192][8]   f32 (output 1)

    unsigned char* ws = (unsigned char*)d_ws;
    size_t ofs = 0;
    auto alloc = [&](size_t bytes) { void* p = ws + ofs; ofs += (bytes + 255) & ~(size_t)255; return p; };

    bf16*  xbf  = (bf16*)alloc((size_t)MT * DM * 2);          // 16.8 MB (swizzled)
    bf16*  WiT  = (bf16*)alloc((size_t)DM * DM * 2);          //  2.1 MB (swizzled)
    bf16*  g    = (bf16*)alloc((size_t)MT * DM * 2);          // 16.8 MB (linear)
    float* sp   = (float*)alloc((size_t)NB * DM * 4);         // 16 KB
    bf16*  W1T  = (bf16*)alloc((size_t)NH * DF * DM * 2);     // 67.1 MB [hf][d] swizzled
    bf16*  W2T  = (bf16*)alloc((size_t)NH * DF * DM * 2);     // 67.1 MB [d][hf] swizzled
    bf16*  hp   = (bf16*)alloc((size_t)MQ * NH * DF * 2);     // 134.2 MB [t][hf] swizzled (per quarter)
    float* part = (float*)alloc((size_t)(NKS - 1) * MQ * DM * 4);  // 58.7 MB
    const long pStride = (long)MQ * DM;

    // stage 0: conversions / transposes / projections
    k_cvtx<<<(MT * DM) / (256 * 8), 256, 0, stream>>>(x, xbf);
    k_tcvt2<<<dim3(DM / 64, DM / 64, 1), 256, 0, stream>>>(Wi, WiT, DM, DM, 0, 0);
    k_sproj2<<<dim3(DM / 16, NB), 256, 0, stream>>>(rs, Ws, bs, sp);

    // stage 1: input proj -> gelu(combined) -> g, then gate weights
    k_g2<0, 0><<<(MT / 256) * (DM / 256), 512, 0, stream>>>(
        xbf, DM, WiT, DM, DM, 0, MT / 256, DM / 256,
        g, nullptr, DM, bi, sp, nullptr, nullptr, 0);
    k_gate<<<MT / 4, 256, 0, stream>>>(g, Wg, bg, wout);

    // weight transposes
    k_tcvt2<<<dim3(DF / 64, DM / 64, NH), 256, 0, stream>>>(
        W1, W1T, DF, DM, (long)DM * DF, (long)DF * DM);
    k_tcvt2<<<dim3(DM / 64, DF / 64, NH), 256, 0, stream>>>(
        W2, W2T, DM, (long)NH * DF, (long)DF * DM, DF);

    // stage 2: per M-quarter: gemm1 (all heads) -> hp ; gemm2 (K-split 8) ; reduce
    for (int q = 0; q < MT / MQ; ++q) {
        const bf16*  xq = xbf + (size_t)q * MQ * DM;
        const float* wq = wout + (size_t)q * MQ * NH;
        float*       oq = out + (size_t)q * MQ * DM;
        k_g2<1, 1><<<(MQ / 256) * (NH * DF / 256), 512, 0, stream>>>(
            xq, DM, W1T, DM, DM, 0, MQ / 256, NH * DF / 256,
            hp, nullptr, (long)NH * DF, b1, wq, nullptr, nullptr, 0);
        k_g2<2, 2><<<(MQ / 256) * (DM / 256) * NKS, 512, 0, stream>>>(
            hp, (long)NH * DF, W2T, (long)NH * DF, KC, KC, MQ / 256, DM / 256,
            nullptr, oq, DM, nullptr, wq, b2, part, pStride);
        k_red<<<(MQ * DM) / (256 * 4), 256, 0, stream>>>(oq, part, pStride, NKS - 1);
    }
    (void)in_sizes; (void)n_in; (void)out_size;
}